// Round 5
// baseline (1659.649 us; speedup 1.0000x reference)
//
#include <hip/hip_runtime.h>
#include <math.h>
#include <stdint.h>

typedef __attribute__((ext_vector_type(8))) short short8;
typedef __attribute__((ext_vector_type(4))) float floatx4;

// fp32 -> (bf16 hi | bf16 lo) packed u32.  hi = RNE(x), lo = RNE(x - hi).
__device__ __forceinline__ uint32_t pack_hilo(float x) {
    uint32_t u = __float_as_uint(x);
    uint32_t hi = (u + 0x7FFFu + ((u >> 16) & 1u)) & 0xFFFF0000u;
    float r = x - __uint_as_float(hi);
    uint32_t v = __float_as_uint(r);
    uint32_t lo = ((v + 0x7FFFu + ((v >> 16) & 1u)) >> 16) & 0xFFFFu;
    return hi | lo;
}

// ---------------------------------------------------------------------------
// Prep: x (64,256,HW) fp32 -> xh,xl (64,HW,256) bf16 shorts (ci contiguous).
// ---------------------------------------------------------------------------
__global__ __launch_bounds__(256) void prep_x_split(
    const float* __restrict__ x, short* __restrict__ xh, short* __restrict__ xl,
    int HW)
{
    const int b = blockIdx.z, c0 = blockIdx.y * 64, p0 = blockIdx.x * 64;
    const int tid = threadIdx.x;
    const int a = tid & 63, g = tid >> 6;
    __shared__ uint32_t t[64][65];
    #pragma unroll
    for (int i = 0; i < 16; ++i) {
        int c = g + i * 4;
        int p = p0 + a;
        float v = (p < HW) ? x[((size_t)(b * 256) + c0 + c) * HW + p] : 0.0f;
        t[c][a] = pack_hilo(v);
    }
    __syncthreads();
    const int j = tid & 31;
    const int gg = tid >> 5;
    #pragma unroll
    for (int i = 0; i < 8; ++i) {
        int p = gg + i * 8;
        if (p0 + p < HW) {
            uint32_t w0 = t[2 * j][p], w1 = t[2 * j + 1][p];
            size_t o = ((size_t)b * HW + p0 + p) * 256 + c0 + 2 * j;
            *(uint32_t*)(xh + o) = (w0 >> 16) | (w1 & 0xFFFF0000u);
            *(uint32_t*)(xl + o) = (w0 & 0xFFFFu) | (w1 << 16);
        }
    }
}

// ---------------------------------------------------------------------------
// Prep: w (256,256,3,3) fp32 -> wh,wl (9,256co,256ci) bf16 shorts.
// ---------------------------------------------------------------------------
__global__ __launch_bounds__(256) void prep_w_split(
    const float* __restrict__ w, short* __restrict__ wh, short* __restrict__ wl)
{
    const int idx = blockIdx.x * 256 + threadIdx.x;
    const int co = idx >> 7, jp = idx & 127;
    const float* s0 = w + ((size_t)co * 256 + 2 * jp) * 9;
    #pragma unroll
    for (int r = 0; r < 9; ++r) {
        uint32_t q0 = pack_hilo(s0[r]);
        uint32_t q1 = pack_hilo(s0[9 + r]);
        size_t o = (size_t)r * 65536 + (size_t)co * 256 + 2 * jp;
        *(uint32_t*)(wh + o) = (q0 >> 16) | (q1 & 0xFFFF0000u);
        *(uint32_t*)(wl + o) = (q0 & 0xFFFFu) | (q1 << 16);
    }
}

// ===========================================================================
// Shared MFMA conv body (register-prefetch pipelined).
// Block tile 128co x 128px, K = 9 taps x 256 ci in 72 chunks of 32 ci.
// Chunk k+1's global loads are issued right after staging chunk k, so the
// vmcnt wait lands after the MFMAs (latency hidden behind compute).
// ===========================================================================
__device__ __forceinline__ void conv_body(
    const short* __restrict__ xh, const short* __restrict__ xl,
    const short* __restrict__ wh, const short* __restrict__ wl,
    const float* __restrict__ bias,
    const float* __restrict__ gam, const float* __restrict__ bet,
    const float* __restrict__ mu,  const float* __restrict__ var,
    float* __restrict__ out,
    int b, int co0, int p0, int H, int W,
    short* a_h, short* a_l, short* b_h, short* b_l)
{
    const int HW = H * W;
    const int Wo = W - 2, P = Wo * Wo;
    const int tid  = threadIdx.x;
    const int wave = tid >> 6, lane = tid & 63;
    const int l15  = lane & 15, quad = lane >> 4;

    const int row  = tid >> 1;
    const int half = tid & 1;

    const int pxs = p0 + row;
    const int pc  = (pxs < P) ? pxs : 0;
    const int oy  = pc / Wo, ox = pc % Wo;
    const size_t xbase = ((size_t)b * HW + oy * W + ox) * 256;
    const size_t wbase = (size_t)(co0 + row) * 256;

    floatx4 acc[2][8];
    #pragma unroll
    for (int s = 0; s < 2; ++s)
        #pragma unroll
        for (int t = 0; t < 8; ++t) acc[s][t] = (floatx4){0.f, 0.f, 0.f, 0.f};

    const int aoff0 = (wave * 32 + l15) * 32 + quad * 8;
    const int aoff1 = aoff0 + 16 * 32;
    int boff[8];
    #pragma unroll
    for (int t = 0; t < 8; ++t) boff[t] = (t * 16 + l15) * 32 + quad * 8;

    const int dst = row * 32 + half * 16;

    uint4 pre[8];
    // prologue: load chunk 0 (r=0, c4=0)
    {
        const int cio = half * 16;
        const uint4* s_ah = (const uint4*)(wh + wbase + cio);
        const uint4* s_al = (const uint4*)(wl + wbase + cio);
        const uint4* s_bh = (const uint4*)(xh + xbase + cio);
        const uint4* s_bl = (const uint4*)(xl + xbase + cio);
        pre[0] = s_ah[0]; pre[1] = s_ah[1];
        pre[2] = s_al[0]; pre[3] = s_al[1];
        pre[4] = s_bh[0]; pre[5] = s_bh[1];
        pre[6] = s_bl[0]; pre[7] = s_bl[1];
    }

    for (int k = 0; k < 72; ++k) {
        __syncthreads();   // previous chunk's frag reads complete
        *(uint4*)(a_h + dst)     = pre[0];
        *(uint4*)(a_h + dst + 8) = pre[1];
        *(uint4*)(a_l + dst)     = pre[2];
        *(uint4*)(a_l + dst + 8) = pre[3];
        *(uint4*)(b_h + dst)     = pre[4];
        *(uint4*)(b_h + dst + 8) = pre[5];
        *(uint4*)(b_l + dst)     = pre[6];
        *(uint4*)(b_l + dst + 8) = pre[7];
        __syncthreads();   // staging visible
        // prefetch chunk k+1 (vmcnt waited at next iteration's ds_write)
        if (k + 1 < 72) {
            const int kk = k + 1;
            const int r = kk >> 3, c4 = kk & 7;
            const int ry = r / 3, rx = r - ry * 3;
            const int cio = c4 * 32 + half * 16;
            const size_t xsrc = xbase + (size_t)(ry * W + rx) * 256 + cio;
            const size_t wsrc = (size_t)r * 65536 + wbase + cio;
            const uint4* s_ah = (const uint4*)(wh + wsrc);
            const uint4* s_al = (const uint4*)(wl + wsrc);
            const uint4* s_bh = (const uint4*)(xh + xsrc);
            const uint4* s_bl = (const uint4*)(xl + xsrc);
            pre[0] = s_ah[0]; pre[1] = s_ah[1];
            pre[2] = s_al[0]; pre[3] = s_al[1];
            pre[4] = s_bh[0]; pre[5] = s_bh[1];
            pre[6] = s_bl[0]; pre[7] = s_bl[1];
        }
        // compute chunk k
        short8 a0h = *(const short8*)(a_h + aoff0);
        short8 a0l = *(const short8*)(a_l + aoff0);
        short8 a1h = *(const short8*)(a_h + aoff1);
        short8 a1l = *(const short8*)(a_l + aoff1);
        #pragma unroll
        for (int t = 0; t < 8; ++t) {
            short8 vh = *(const short8*)(b_h + boff[t]);
            short8 vl = *(const short8*)(b_l + boff[t]);
            acc[0][t] = __builtin_amdgcn_mfma_f32_16x16x32_bf16(a0h, vh, acc[0][t], 0, 0, 0);
            acc[1][t] = __builtin_amdgcn_mfma_f32_16x16x32_bf16(a1h, vh, acc[1][t], 0, 0, 0);
            acc[0][t] = __builtin_amdgcn_mfma_f32_16x16x32_bf16(a0h, vl, acc[0][t], 0, 0, 0);
            acc[1][t] = __builtin_amdgcn_mfma_f32_16x16x32_bf16(a1h, vl, acc[1][t], 0, 0, 0);
            acc[0][t] = __builtin_amdgcn_mfma_f32_16x16x32_bf16(a0l, vh, acc[0][t], 0, 0, 0);
            acc[1][t] = __builtin_amdgcn_mfma_f32_16x16x32_bf16(a1l, vh, acc[1][t], 0, 0, 0);
        }
    }

    // epilogue: D layout col(px)=lane&15, row(co)=quad*4+reg  [verified m89/m91]
    #pragma unroll
    for (int s = 0; s < 2; ++s) {
        const int cobase = co0 + wave * 32 + s * 16 + quad * 4;
        #pragma unroll
        for (int reg = 0; reg < 4; ++reg) {
            const int co = cobase + reg;
            const float A   = gam[co] * rsqrtf(var[co] + 1e-5f);
            const float OFF = fmaf(bias[co] - mu[co], A, bet[co]);
            float* orow = out + ((size_t)(b * 256 + co)) * P;
            #pragma unroll
            for (int t = 0; t < 8; ++t) {
                int px = p0 + t * 16 + l15;
                if (px < P)
                    orow[px] = fmaxf(fmaf(acc[s][t][reg], A, OFF), 0.0f);
            }
        }
    }
}

// ---------------------------------------------------------------------------
// conv_search: grid (7, 2, 64)
// ---------------------------------------------------------------------------
__global__ __launch_bounds__(256) void conv_mfma_search(
    const short* __restrict__ xh, const short* __restrict__ xl,
    const short* __restrict__ wh, const short* __restrict__ wl,
    const float* __restrict__ bias,
    const float* __restrict__ gam, const float* __restrict__ bet,
    const float* __restrict__ mu,  const float* __restrict__ var,
    float* __restrict__ out, int H, int W)
{
    __shared__ __align__(16) short a_h[128 * 32], a_l[128 * 32];
    __shared__ __align__(16) short b_h[128 * 32], b_l[128 * 32];
    conv_body(xh, xl, wh, wl, bias, gam, bet, mu, var, out,
              blockIdx.z, blockIdx.y * 128, blockIdx.x * 128, H, W,
              a_h, a_l, b_h, b_l);
}

// ---------------------------------------------------------------------------
// conv_tmpl: all 3 template scales in one dispatch. grid (2, 192):
// blockIdx.x = co half, blockIdx.y = scale*64 + b.
// ---------------------------------------------------------------------------
__global__ __launch_bounds__(256) void conv_mfma_tmpl(
    const short* __restrict__ xhL, const short* __restrict__ xlL,
    const short* __restrict__ xhM, const short* __restrict__ xlM,
    const short* __restrict__ xhS, const short* __restrict__ xlS,
    const short* __restrict__ wh,  const short* __restrict__ wl,
    const float* __restrict__ bias,
    const float* __restrict__ gam, const float* __restrict__ bet,
    const float* __restrict__ mu,  const float* __restrict__ var,
    float* __restrict__ outL, float* __restrict__ outM, float* __restrict__ outS)
{
    __shared__ __align__(16) short a_h[128 * 32], a_l[128 * 32];
    __shared__ __align__(16) short b_h[128 * 32], b_l[128 * 32];
    const int sb = blockIdx.y;
    const int scale = sb >> 6, b = sb & 63;
    const short* xh = (scale == 0) ? xhL : (scale == 1) ? xhM : xhS;
    const short* xl = (scale == 0) ? xlL : (scale == 1) ? xlM : xlS;
    float* out      = (scale == 0) ? outL : (scale == 1) ? outM : outS;
    const int H     = (scale == 0) ? 9 : (scale == 1) ? 7 : 5;
    conv_body(xh, xl, wh, wl, bias, gam, bet, mu, var, out,
              b, blockIdx.x * 128, 0, H, H,
              a_h, a_l, b_h, b_l);
}

// ---------------------------------------------------------------------------
// corr v2 (R4-proven): one wave per (b,c); templates in VGPRs; 4-wide outputs
// with b128 sliding-window reads from a padded 33x36 LDS plane. grid (64,64)
// ---------------------------------------------------------------------------
__global__ __launch_bounds__(256) void corr_kernel(
    const float* __restrict__ lf, const float* __restrict__ mf,
    const float* __restrict__ sf, const float* __restrict__ s,
    float* __restrict__ lc, float* __restrict__ mc, float* __restrict__ sc)
{
    const int b = blockIdx.y;
    const int wave = threadIdx.x >> 6, lane = threadIdx.x & 63;
    const int c = blockIdx.x * 4 + wave;
    const int bc = b * 256 + c;

    __shared__ __align__(16) float sp[4][33 * 36];
    __shared__ float tw[4][96];

    float* P = sp[wave];
    for (int i = lane; i < 33 * 36; i += 64) P[i] = 0.0f;
    if (lane < 49) tw[wave][lane]      = lf[(size_t)bc * 49 + lane];
    if (lane < 25) tw[wave][49 + lane] = mf[(size_t)bc * 25 + lane];
    if (lane < 9)  tw[wave][74 + lane] = sf[(size_t)bc * 9 + lane];
    for (int i = lane; i < 841; i += 64) {
        int y = i / 29, x = i - y * 29;
        P[(y + 2) * 36 + (x + 2)] = s[(size_t)bc * 841 + i];
    }
    __syncthreads();

    {
        float t7[49];
        #pragma unroll
        for (int k = 0; k < 49; ++k) t7[k] = tw[wave][k];
        #pragma unroll
        for (int it = 0; it < 3; ++it) {
            int og = lane + it * 64;
            bool v = (og < 189);
            int y = v ? (og / 7) : 0;
            int xg = og - (og / 7) * 7;
            int x0 = xg * 4;
            float a0 = 0, a1 = 0, a2 = 0, a3 = 0;
            #pragma unroll
            for (int dy = 0; dy < 7; ++dy) {
                const float* rp = P + (y + dy) * 36 + x0;
                float4 fA = *(const float4*)rp;
                float4 fB = *(const float4*)(rp + 4);
                float4 fC = *(const float4*)(rp + 8);
                float f[12] = {fA.x, fA.y, fA.z, fA.w, fB.x, fB.y, fB.z, fB.w,
                               fC.x, fC.y, fC.z, fC.w};
                #pragma unroll
                for (int dx = 0; dx < 7; ++dx) {
                    float t = t7[dy * 7 + dx];
                    a0 = fmaf(t, f[dx], a0);
                    a1 = fmaf(t, f[dx + 1], a1);
                    a2 = fmaf(t, f[dx + 2], a2);
                    a3 = fmaf(t, f[dx + 3], a3);
                }
            }
            if (v) {
                size_t o = (size_t)bc * 729 + y * 27 + x0;
                lc[o] = a0;
                lc[o + 1] = a1;
                lc[o + 2] = a2;
                if (x0 + 3 < 27) lc[o + 3] = a3;
            }
        }
    }
    {
        float t5[25];
        #pragma unroll
        for (int k = 0; k < 25; ++k) t5[k] = tw[wave][49 + k];
        #pragma unroll
        for (int it = 0; it < 3; ++it) {
            int og = lane + it * 64;
            bool v = (og < 175);
            int y = v ? (og / 7) : 0;
            int xg = og - (og / 7) * 7;
            int x0 = xg * 4;
            float a0 = 0, a1 = 0, a2 = 0, a3 = 0;
            #pragma unroll
            for (int dy = 0; dy < 5; ++dy) {
                const float* rp = P + (y + 2 + dy) * 36 + x0;
                float4 fA = *(const float4*)rp;
                float4 fB = *(const float4*)(rp + 4);
                float4 fC = *(const float4*)(rp + 8);
                float f[12] = {fA.x, fA.y, fA.z, fA.w, fB.x, fB.y, fB.z, fB.w,
                               fC.x, fC.y, fC.z, fC.w};
                #pragma unroll
                for (int dx = 0; dx < 5; ++dx) {
                    float t = t5[dy * 5 + dx];
                    a0 = fmaf(t, f[2 + dx], a0);
                    a1 = fmaf(t, f[3 + dx], a1);
                    a2 = fmaf(t, f[4 + dx], a2);
                    a3 = fmaf(t, f[5 + dx], a3);
                }
            }
            if (v) {
                size_t o = (size_t)bc * 625 + y * 25 + x0;
                mc[o] = a0;
                if (x0 + 1 < 25) mc[o + 1] = a1;
                if (x0 + 2 < 25) mc[o + 2] = a2;
                if (x0 + 3 < 25) mc[o + 3] = a3;
            }
        }
    }
    {
        float t3[9];
        #pragma unroll
        for (int k = 0; k < 9; ++k) t3[k] = tw[wave][74 + k];
        #pragma unroll
        for (int it = 0; it < 3; ++it) {
            int og = lane + it * 64;
            bool v = (og < 189);
            int y = v ? (og / 7) : 0;
            int xg = og - (og / 7) * 7;
            int x0 = xg * 4;
            float a0 = 0, a1 = 0, a2 = 0, a3 = 0;
            #pragma unroll
            for (int dy = 0; dy < 3; ++dy) {
                const float* rp = P + (y + 2 + dy) * 36 + x0;
                float4 fA = *(const float4*)rp;
                float4 fB = *(const float4*)(rp + 4);
                float f[8] = {fA.x, fA.y, fA.z, fA.w, fB.x, fB.y, fB.z, fB.w};
                #pragma unroll
                for (int dx = 0; dx < 3; ++dx) {
                    float t = t3[dy * 3 + dx];
                    a0 = fmaf(t, f[2 + dx], a0);
                    a1 = fmaf(t, f[3 + dx], a1);
                    a2 = fmaf(t, f[4 + dx], a2);
                    a3 = fmaf(t, f[5 + dx], a3);
                }
            }
            if (v) {
                size_t o = (size_t)bc * 729 + y * 27 + x0;
                sc[o] = a0;
                sc[o + 1] = a1;
                sc[o + 2] = a2;
                if (x0 + 3 < 27) sc[o + 3] = a3;
            }
        }
    }
}

// ---------------------------------------------------------------------------
// head v2 (R4-proven): sigmoid(w2 . relu(BN(W1.x+b1)) + b2), split-bf16 MFMA.
// grid (ceil(Np/128), 64)
// ---------------------------------------------------------------------------
__global__ __launch_bounds__(256) void head_mfma_kernel(
    const float* __restrict__ X,
    const float* __restrict__ w1,
    const float* __restrict__ b1,
    const float* __restrict__ g1, const float* __restrict__ be1,
    const float* __restrict__ m1, const float* __restrict__ v1,
    const float* __restrict__ w2, const float* __restrict__ b2,
    float* __restrict__ out,
    int Np)
{
    const int b  = blockIdx.y;
    const int p0 = blockIdx.x * 128;
    const int tid = threadIdx.x;
    const int wave = tid >> 6, lane = tid & 63;
    const int l15 = lane & 15, quad = lane >> 4;

    __shared__ __align__(16) short Ah[256 * 32], Al[256 * 32];
    __shared__ __align__(16) short Bh[128 * 40], Bl[128 * 40];
    __shared__ float red[128 * 17];

    floatx4 acc[4][8];
    #pragma unroll
    for (int m = 0; m < 4; ++m)
        #pragma unroll
        for (int n = 0; n < 8; ++n) acc[m][n] = (floatx4){0.f, 0.f, 0.f, 0.f};

    const int cp  = tid & 15;
    const int pxq = tid >> 4;

    for (int k0 = 0; k0 < 256; k0 += 32) {
        {
            const float* src = w1 + (size_t)tid * 256 + k0;
            uint32_t h[16], l[16];
            #pragma unroll
            for (int q = 0; q < 8; ++q) {
                float4 v4 = *(const float4*)(src + q * 4);
                uint32_t pa = pack_hilo(v4.x), pb = pack_hilo(v4.y);
                uint32_t pc = pack_hilo(v4.z), pd = pack_hilo(v4.w);
                h[q * 2]     = (pa >> 16) | (pb & 0xFFFF0000u);
                h[q * 2 + 1] = (pc >> 16) | (pd & 0xFFFF0000u);
                l[q * 2]     = (pa & 0xFFFFu) | (pb << 16);
                l[q * 2 + 1] = (pc & 0xFFFFu) | (pd << 16);
            }
            #pragma unroll
            for (int q = 0; q < 4; ++q) {
                uint4 uh; uh.x = h[q*4]; uh.y = h[q*4+1]; uh.z = h[q*4+2]; uh.w = h[q*4+3];
                uint4 ul; ul.x = l[q*4]; ul.y = l[q*4+1]; ul.z = l[q*4+2]; ul.w = l[q*4+3];
                *(uint4*)(Ah + tid * 32 + q * 8) = uh;
                *(uint4*)(Al + tid * 32 + q * 8) = ul;
            }
        }
        #pragma unroll
        for (int halfp = 0; halfp < 2; ++halfp) {
            int pxl = halfp * 64 + pxq * 4;
            int gp = p0 + pxl;
            const float* r0 = X + ((size_t)(b * 256) + k0 + 2 * cp) * Np + gp;
            const float* r1 = r0 + Np;
            #pragma unroll
            for (int j = 0; j < 4; ++j) {
                float u = (gp + j < Np) ? r0[j] : 0.0f;
                float v = (gp + j < Np) ? r1[j] : 0.0f;
                uint32_t hu = pack_hilo(u), hv = pack_hilo(v);
                int o = (pxl + j) * 40 + 2 * cp;
                *(uint32_t*)(Bh + o) = (hu >> 16) | (hv & 0xFFFF0000u);
                *(uint32_t*)(Bl + o) = (hu & 0xFFFFu) | (hv << 16);
            }
        }
        __syncthreads();
        short8 amh[4], aml[4];
        #pragma unroll
        for (int m = 0; m < 4; ++m) {
            int ao = (wave * 64 + m * 16 + l15) * 32 + quad * 8;
            amh[m] = *(const short8*)(Ah + ao);
            aml[m] = *(const short8*)(Al + ao);
        }
        #pragma unroll
        for (int n = 0; n < 8; ++n) {
            int bo = (n * 16 + l15) * 40 + quad * 8;
            short8 bh = *(const short8*)(Bh + bo);
            short8 bl = *(const short8*)(Bl + bo);
            #pragma unroll
            for (int m = 0; m < 4; ++m) {
                acc[m][n] = __builtin_amdgcn_mfma_f32_16x16x32_bf16(amh[m], bh, acc[m][n], 0, 0, 0);
                acc[m][n] = __builtin_amdgcn_mfma_f32_16x16x32_bf16(amh[m], bl, acc[m][n], 0, 0, 0);
                acc[m][n] = __builtin_amdgcn_mfma_f32_16x16x32_bf16(aml[m], bh, acc[m][n], 0, 0, 0);
            }
        }
        __syncthreads();
    }

    float Ac[16], Oc[16], Wc[16];
    #pragma unroll
    for (int m = 0; m < 4; ++m)
        #pragma unroll
        for (int reg = 0; reg < 4; ++reg) {
            int co = wave * 64 + m * 16 + quad * 4 + reg;
            float A = g1[co] * rsqrtf(v1[co] + 1e-5f);
            Ac[m * 4 + reg] = A;
            Oc[m * 4 + reg] = fmaf(b1[co] - m1[co], A, be1[co]);
            Wc[m * 4 + reg] = w2[co];
        }
    #pragma unroll
    for (int n = 0; n < 8; ++n) {
        float part = 0.0f;
        #pragma unroll
        for (int m = 0; m < 4; ++m)
            #pragma unroll
            for (int reg = 0; reg < 4; ++reg) {
                float y = fmaxf(fmaf(acc[m][n][reg], Ac[m * 4 + reg], Oc[m * 4 + reg]), 0.0f);
                part = fmaf(Wc[m * 4 + reg], y, part);
            }
        red[(n * 16 + l15) * 17 + wave * 4 + quad] = part;
    }
    __syncthreads();
    if (tid < 128) {
        float z = b2[0];
        #pragma unroll
        for (int k = 0; k < 16; ++k) z += red[tid * 17 + k];
        if (p0 + tid < Np)
            out[(size_t)b * Np + p0 + tid] = 1.0f / (1.0f + expf(-z));
    }
}

// ---------------------------------------------------------------------------
extern "C" void kernel_launch(void* const* d_in, const int* in_sizes, int n_in,
                              void* d_out, int out_size, void* d_ws, size_t ws_size,
                              hipStream_t stream)
{
    const float* large  = (const float*)d_in[0];
    const float* medium = (const float*)d_in[1];
    const float* small  = (const float*)d_in[2];
    const float* search = (const float*)d_in[3];
    const float* wt  = (const float*)d_in[4];
    const float* bt  = (const float*)d_in[5];
    const float* gt  = (const float*)d_in[6];
    const float* bet = (const float*)d_in[7];
    const float* mt  = (const float*)d_in[8];
    const float* vt  = (const float*)d_in[9];
    const float* wsc = (const float*)d_in[10];
    const float* bs  = (const float*)d_in[11];
    const float* gs  = (const float*)d_in[12];
    const float* bes = (const float*)d_in[13];
    const float* ms  = (const float*)d_in[14];
    const float* vs  = (const float*)d_in[15];
    const float* w1  = (const float*)d_in[16];
    const float* b1  = (const float*)d_in[17];
    const float* g1  = (const float*)d_in[18];
    const float* be1 = (const float*)d_in[19];
    const float* m1  = (const float*)d_in[20];
    const float* v1  = (const float*)d_in[21];
    const float* w2  = (const float*)d_in[22];
    const float* b2  = (const float*)d_in[23];

    float* ws = (float*)d_ws;
    size_t off = 0;
    float* lf = ws + off; off += (size_t)64 * 256 * 49;
    float* mf = ws + off; off += (size_t)64 * 256 * 25;
    float* sf = ws + off; off += (size_t)64 * 256 * 9;
    float* sq = ws + off; off += (size_t)64 * 256 * 841;
    float* lc = ws + off; off += (size_t)64 * 256 * 729;
    float* mc = ws + off; off += (size_t)64 * 256 * 625;
    float* sc = ws + off; off += (size_t)64 * 256 * 729;

    // Aliased prep buffers (dead before corr writes lc/mc/sc):
    short* xh_s = (short*)lc;
    short* xl_s = (short*)lc + 15745024;
    short* base = (short*)sc;
    short* xh_L = base;
    short* xl_L = base + 1327104;
    short* xh_M = base + 2654208;
    short* xl_M = base + 3457024;
    short* xh_S = base + 4259840;
    short* xl_S = base + 4669440;
    short* wh_t = base + 5079040;
    short* wl_t = base + 5668864;
    short* wh_s = base + 6258688;
    short* wl_s = base + 6848512;

    dim3 blk(256);
    prep_w_split<<<dim3(128), blk, 0, stream>>>(wt,  wh_t, wl_t);
    prep_w_split<<<dim3(128), blk, 0, stream>>>(wsc, wh_s, wl_s);
    prep_x_split<<<dim3(16, 4, 64), blk, 0, stream>>>(search, xh_s, xl_s, 961);
    prep_x_split<<<dim3(2, 4, 64),  blk, 0, stream>>>(large,  xh_L, xl_L, 81);
    prep_x_split<<<dim3(1, 4, 64),  blk, 0, stream>>>(medium, xh_M, xl_M, 49);
    prep_x_split<<<dim3(1, 4, 64),  blk, 0, stream>>>(small,  xh_S, xl_S, 25);

    conv_mfma_tmpl<<<dim3(2, 192), blk, 0, stream>>>(
        xh_L, xl_L, xh_M, xl_M, xh_S, xl_S, wh_t, wl_t,
        bt, gt, bet, mt, vt, lf, mf, sf);
    conv_mfma_search<<<dim3(7, 2, 64), blk, 0, stream>>>(
        xh_s, xl_s, wh_s, wl_s, bs, gs, bes, ms, vs, sq, 31, 31);

    corr_kernel<<<dim3(64, 64), blk, 0, stream>>>(lf, mf, sf, sq, lc, mc, sc);

    float* outp = (float*)d_out;
    head_mfma_kernel<<<dim3(6, 64), blk, 0, stream>>>(lc, w1, b1, g1, be1, m1, v1, w2, b2, outp, 729);
    head_mfma_kernel<<<dim3(5, 64), blk, 0, stream>>>(mc, w1, b1, g1, be1, m1, v1, w2, b2, outp + 46656, 625);
    head_mfma_kernel<<<dim3(6, 64), blk, 0, stream>>>(sc, w1, b1, g1, be1, m1, v1, w2, b2, outp + 86656, 729);
}

// Round 6
// 974.595 us; speedup vs baseline: 1.7029x; 1.7029x over previous
//
#include <hip/hip_runtime.h>
#include <math.h>
#include <stdint.h>

typedef __attribute__((ext_vector_type(8))) short short8;
typedef __attribute__((ext_vector_type(4))) float floatx4;

// fp32 -> (bf16 hi | bf16 lo) packed u32.  hi = RNE(x), lo = RNE(x - hi).
__device__ __forceinline__ uint32_t pack_hilo(float x) {
    uint32_t u = __float_as_uint(x);
    uint32_t hi = (u + 0x7FFFu + ((u >> 16) & 1u)) & 0xFFFF0000u;
    float r = x - __uint_as_float(hi);
    uint32_t v = __float_as_uint(r);
    uint32_t lo = ((v + 0x7FFFu + ((v >> 16) & 1u)) >> 16) & 0xFFFFu;
    return hi | lo;
}

// ---------------------------------------------------------------------------
// Prep: x (64,256,HW) fp32 -> xh,xl (64,HW,256) bf16 shorts (ci contiguous).
// ---------------------------------------------------------------------------
__global__ __launch_bounds__(256) void prep_x_split(
    const float* __restrict__ x, short* __restrict__ xh, short* __restrict__ xl,
    int HW)
{
    const int b = blockIdx.z, c0 = blockIdx.y * 64, p0 = blockIdx.x * 64;
    const int tid = threadIdx.x;
    const int a = tid & 63, g = tid >> 6;
    __shared__ uint32_t t[64][65];
    #pragma unroll
    for (int i = 0; i < 16; ++i) {
        int c = g + i * 4;
        int p = p0 + a;
        float v = (p < HW) ? x[((size_t)(b * 256) + c0 + c) * HW + p] : 0.0f;
        t[c][a] = pack_hilo(v);
    }
    __syncthreads();
    const int j = tid & 31;
    const int gg = tid >> 5;
    #pragma unroll
    for (int i = 0; i < 8; ++i) {
        int p = gg + i * 8;
        if (p0 + p < HW) {
            uint32_t w0 = t[2 * j][p], w1 = t[2 * j + 1][p];
            size_t o = ((size_t)b * HW + p0 + p) * 256 + c0 + 2 * j;
            *(uint32_t*)(xh + o) = (w0 >> 16) | (w1 & 0xFFFF0000u);
            *(uint32_t*)(xl + o) = (w0 & 0xFFFFu) | (w1 << 16);
        }
    }
}

// ---------------------------------------------------------------------------
// Prep: w (256,256,3,3) fp32 -> wh,wl (9,256co,256ci) bf16 shorts.
// ---------------------------------------------------------------------------
__global__ __launch_bounds__(256) void prep_w_split(
    const float* __restrict__ w, short* __restrict__ wh, short* __restrict__ wl)
{
    const int idx = blockIdx.x * 256 + threadIdx.x;
    const int co = idx >> 7, jp = idx & 127;
    const float* s0 = w + ((size_t)co * 256 + 2 * jp) * 9;
    #pragma unroll
    for (int r = 0; r < 9; ++r) {
        uint32_t q0 = pack_hilo(s0[r]);
        uint32_t q1 = pack_hilo(s0[9 + r]);
        size_t o = (size_t)r * 65536 + (size_t)co * 256 + 2 * jp;
        *(uint32_t*)(wh + o) = (q0 >> 16) | (q1 & 0xFFFF0000u);
        *(uint32_t*)(wl + o) = (q0 & 0xFFFFu) | (q1 << 16);
    }
}

// ===========================================================================
// Shared MFMA conv body — R4-proven staging (no cross-barrier registers),
// plus NT masking: n-subtiles beyond ceil((P-p0)/16) are skipped (MFMA and
// B-staging both), which matters for the tiny template tiles (P=49/25/9).
// Block tile 128co x 128px, K = 9 taps x 256 ci in 72 chunks of 32 ci.
// ===========================================================================
__device__ __forceinline__ void conv_body(
    const short* __restrict__ xh, const short* __restrict__ xl,
    const short* __restrict__ wh, const short* __restrict__ wl,
    const float* __restrict__ bias,
    const float* __restrict__ gam, const float* __restrict__ bet,
    const float* __restrict__ mu,  const float* __restrict__ var,
    float* __restrict__ out,
    int b, int co0, int p0, int H, int W,
    short* a_h, short* a_l, short* b_h, short* b_l)
{
    const int HW = H * W;
    const int Wo = W - 2, P = Wo * Wo;
    const int tid  = threadIdx.x;
    const int wave = tid >> 6, lane = tid & 63;
    const int l15  = lane & 15, quad = lane >> 4;

    int NT = (P - p0 + 15) >> 4;            // active 16-px subtiles (1..8)
    if (NT > 8) NT = 8;

    const int row  = tid >> 1;
    const int half = tid & 1;
    const bool stB = (row < NT * 16);       // B-staging needed for this row?

    const int pxs = p0 + row;
    const int pc  = (pxs < P) ? pxs : 0;
    const int oy  = pc / Wo, ox = pc % Wo;
    const size_t xbase = ((size_t)b * HW + oy * W + ox) * 256;
    const size_t wbase = (size_t)(co0 + row) * 256;

    floatx4 acc[2][8];
    #pragma unroll
    for (int s = 0; s < 2; ++s)
        #pragma unroll
        for (int t = 0; t < 8; ++t) acc[s][t] = (floatx4){0.f, 0.f, 0.f, 0.f};

    const int aoff0 = (wave * 32 + l15) * 32 + quad * 8;
    const int aoff1 = aoff0 + 16 * 32;
    int boff[8];
    #pragma unroll
    for (int t = 0; t < 8; ++t) boff[t] = (t * 16 + l15) * 32 + quad * 8;

    const int dst = row * 32 + half * 16;

    for (int r = 0; r < 9; ++r) {
        const int ry = r / 3, rx = r - ry * 3;
        const size_t xsrc = xbase + (size_t)(ry * W + rx) * 256;
        const size_t wsrc = (size_t)r * 65536 + wbase;
        for (int c4 = 0; c4 < 8; ++c4) {
            const int cio = c4 * 32 + half * 16;
            {
                const uint4* s_ah = (const uint4*)(wh + wsrc + cio);
                const uint4* s_al = (const uint4*)(wl + wsrc + cio);
                uint4 vah0 = s_ah[0], vah1 = s_ah[1];
                uint4 val0 = s_al[0], val1 = s_al[1];
                *(uint4*)(a_h + dst)     = vah0;
                *(uint4*)(a_h + dst + 8) = vah1;
                *(uint4*)(a_l + dst)     = val0;
                *(uint4*)(a_l + dst + 8) = val1;
                if (stB) {
                    const uint4* s_bh = (const uint4*)(xh + xsrc + cio);
                    const uint4* s_bl = (const uint4*)(xl + xsrc + cio);
                    uint4 vbh0 = s_bh[0], vbh1 = s_bh[1];
                    uint4 vbl0 = s_bl[0], vbl1 = s_bl[1];
                    *(uint4*)(b_h + dst)     = vbh0;
                    *(uint4*)(b_h + dst + 8) = vbh1;
                    *(uint4*)(b_l + dst)     = vbl0;
                    *(uint4*)(b_l + dst + 8) = vbl1;
                }
            }
            __syncthreads();
            short8 a0h = *(const short8*)(a_h + aoff0);
            short8 a0l = *(const short8*)(a_l + aoff0);
            short8 a1h = *(const short8*)(a_h + aoff1);
            short8 a1l = *(const short8*)(a_l + aoff1);
            #pragma unroll
            for (int t = 0; t < 8; ++t) {
                if (t < NT) {
                    short8 vh = *(const short8*)(b_h + boff[t]);
                    short8 vl = *(const short8*)(b_l + boff[t]);
                    acc[0][t] = __builtin_amdgcn_mfma_f32_16x16x32_bf16(a0h, vh, acc[0][t], 0, 0, 0);
                    acc[1][t] = __builtin_amdgcn_mfma_f32_16x16x32_bf16(a1h, vh, acc[1][t], 0, 0, 0);
                    acc[0][t] = __builtin_amdgcn_mfma_f32_16x16x32_bf16(a0h, vl, acc[0][t], 0, 0, 0);
                    acc[1][t] = __builtin_amdgcn_mfma_f32_16x16x32_bf16(a1h, vl, acc[1][t], 0, 0, 0);
                    acc[0][t] = __builtin_amdgcn_mfma_f32_16x16x32_bf16(a0l, vh, acc[0][t], 0, 0, 0);
                    acc[1][t] = __builtin_amdgcn_mfma_f32_16x16x32_bf16(a1l, vh, acc[1][t], 0, 0, 0);
                }
            }
            __syncthreads();
        }
    }

    // epilogue: D layout col(px)=lane&15, row(co)=quad*4+reg  [verified m89/m91]
    #pragma unroll
    for (int s = 0; s < 2; ++s) {
        const int cobase = co0 + wave * 32 + s * 16 + quad * 4;
        #pragma unroll
        for (int reg = 0; reg < 4; ++reg) {
            const int co = cobase + reg;
            const float A   = gam[co] * rsqrtf(var[co] + 1e-5f);
            const float OFF = fmaf(bias[co] - mu[co], A, bet[co]);
            float* orow = out + ((size_t)(b * 256 + co)) * P;
            #pragma unroll
            for (int t = 0; t < 8; ++t) {
                int px = p0 + t * 16 + l15;
                if (px < P)
                    orow[px] = fmaxf(fmaf(acc[s][t][reg], A, OFF), 0.0f);
            }
        }
    }
}

// ---------------------------------------------------------------------------
// conv_search: grid (7, 2, 64)
// ---------------------------------------------------------------------------
__global__ __launch_bounds__(256) void conv_mfma_search(
    const short* __restrict__ xh, const short* __restrict__ xl,
    const short* __restrict__ wh, const short* __restrict__ wl,
    const float* __restrict__ bias,
    const float* __restrict__ gam, const float* __restrict__ bet,
    const float* __restrict__ mu,  const float* __restrict__ var,
    float* __restrict__ out, int H, int W)
{
    __shared__ __align__(16) short a_h[128 * 32], a_l[128 * 32];
    __shared__ __align__(16) short b_h[128 * 32], b_l[128 * 32];
    conv_body(xh, xl, wh, wl, bias, gam, bet, mu, var, out,
              blockIdx.z, blockIdx.y * 128, blockIdx.x * 128, H, W,
              a_h, a_l, b_h, b_l);
}

// ---------------------------------------------------------------------------
// conv_tmpl: all 3 template scales in one dispatch. grid (2, 192):
// blockIdx.x = co half, blockIdx.y = scale*64 + b.
// ---------------------------------------------------------------------------
__global__ __launch_bounds__(256) void conv_mfma_tmpl(
    const short* __restrict__ xhL, const short* __restrict__ xlL,
    const short* __restrict__ xhM, const short* __restrict__ xlM,
    const short* __restrict__ xhS, const short* __restrict__ xlS,
    const short* __restrict__ wh,  const short* __restrict__ wl,
    const float* __restrict__ bias,
    const float* __restrict__ gam, const float* __restrict__ bet,
    const float* __restrict__ mu,  const float* __restrict__ var,
    float* __restrict__ outL, float* __restrict__ outM, float* __restrict__ outS)
{
    __shared__ __align__(16) short a_h[128 * 32], a_l[128 * 32];
    __shared__ __align__(16) short b_h[128 * 32], b_l[128 * 32];
    const int sb = blockIdx.y;
    const int scale = sb >> 6, b = sb & 63;
    const short* xh = (scale == 0) ? xhL : (scale == 1) ? xhM : xhS;
    const short* xl = (scale == 0) ? xlL : (scale == 1) ? xlM : xlS;
    float* out      = (scale == 0) ? outL : (scale == 1) ? outM : outS;
    const int H     = (scale == 0) ? 9 : (scale == 1) ? 7 : 5;
    conv_body(xh, xl, wh, wl, bias, gam, bet, mu, var, out,
              b, blockIdx.x * 128, 0, H, H,
              a_h, a_l, b_h, b_l);
}

// ---------------------------------------------------------------------------
// corr v2 (R4-proven): one wave per (b,c); templates in VGPRs; 4-wide outputs
// with b128 sliding-window reads from a padded 33x36 LDS plane. grid (64,64)
// ---------------------------------------------------------------------------
__global__ __launch_bounds__(256) void corr_kernel(
    const float* __restrict__ lf, const float* __restrict__ mf,
    const float* __restrict__ sf, const float* __restrict__ s,
    float* __restrict__ lc, float* __restrict__ mc, float* __restrict__ sc)
{
    const int b = blockIdx.y;
    const int wave = threadIdx.x >> 6, lane = threadIdx.x & 63;
    const int c = blockIdx.x * 4 + wave;
    const int bc = b * 256 + c;

    __shared__ __align__(16) float sp[4][33 * 36];
    __shared__ float tw[4][96];

    float* P = sp[wave];
    for (int i = lane; i < 33 * 36; i += 64) P[i] = 0.0f;
    if (lane < 49) tw[wave][lane]      = lf[(size_t)bc * 49 + lane];
    if (lane < 25) tw[wave][49 + lane] = mf[(size_t)bc * 25 + lane];
    if (lane < 9)  tw[wave][74 + lane] = sf[(size_t)bc * 9 + lane];
    for (int i = lane; i < 841; i += 64) {
        int y = i / 29, x = i - y * 29;
        P[(y + 2) * 36 + (x + 2)] = s[(size_t)bc * 841 + i];
    }
    __syncthreads();

    {
        float t7[49];
        #pragma unroll
        for (int k = 0; k < 49; ++k) t7[k] = tw[wave][k];
        #pragma unroll
        for (int it = 0; it < 3; ++it) {
            int og = lane + it * 64;
            bool v = (og < 189);
            int y = v ? (og / 7) : 0;
            int xg = og - (og / 7) * 7;
            int x0 = xg * 4;
            float a0 = 0, a1 = 0, a2 = 0, a3 = 0;
            #pragma unroll
            for (int dy = 0; dy < 7; ++dy) {
                const float* rp = P + (y + dy) * 36 + x0;
                float4 fA = *(const float4*)rp;
                float4 fB = *(const float4*)(rp + 4);
                float4 fC = *(const float4*)(rp + 8);
                float f[12] = {fA.x, fA.y, fA.z, fA.w, fB.x, fB.y, fB.z, fB.w,
                               fC.x, fC.y, fC.z, fC.w};
                #pragma unroll
                for (int dx = 0; dx < 7; ++dx) {
                    float t = t7[dy * 7 + dx];
                    a0 = fmaf(t, f[dx], a0);
                    a1 = fmaf(t, f[dx + 1], a1);
                    a2 = fmaf(t, f[dx + 2], a2);
                    a3 = fmaf(t, f[dx + 3], a3);
                }
            }
            if (v) {
                size_t o = (size_t)bc * 729 + y * 27 + x0;
                lc[o] = a0;
                lc[o + 1] = a1;
                lc[o + 2] = a2;
                if (x0 + 3 < 27) lc[o + 3] = a3;
            }
        }
    }
    {
        float t5[25];
        #pragma unroll
        for (int k = 0; k < 25; ++k) t5[k] = tw[wave][49 + k];
        #pragma unroll
        for (int it = 0; it < 3; ++it) {
            int og = lane + it * 64;
            bool v = (og < 175);
            int y = v ? (og / 7) : 0;
            int xg = og - (og / 7) * 7;
            int x0 = xg * 4;
            float a0 = 0, a1 = 0, a2 = 0, a3 = 0;
            #pragma unroll
            for (int dy = 0; dy < 5; ++dy) {
                const float* rp = P + (y + 2 + dy) * 36 + x0;
                float4 fA = *(const float4*)rp;
                float4 fB = *(const float4*)(rp + 4);
                float4 fC = *(const float4*)(rp + 8);
                float f[12] = {fA.x, fA.y, fA.z, fA.w, fB.x, fB.y, fB.z, fB.w,
                               fC.x, fC.y, fC.z, fC.w};
                #pragma unroll
                for (int dx = 0; dx < 5; ++dx) {
                    float t = t5[dy * 5 + dx];
                    a0 = fmaf(t, f[2 + dx], a0);
                    a1 = fmaf(t, f[3 + dx], a1);
                    a2 = fmaf(t, f[4 + dx], a2);
                    a3 = fmaf(t, f[5 + dx], a3);
                }
            }
            if (v) {
                size_t o = (size_t)bc * 625 + y * 25 + x0;
                mc[o] = a0;
                if (x0 + 1 < 25) mc[o + 1] = a1;
                if (x0 + 2 < 25) mc[o + 2] = a2;
                if (x0 + 3 < 25) mc[o + 3] = a3;
            }
        }
    }
    {
        float t3[9];
        #pragma unroll
        for (int k = 0; k < 9; ++k) t3[k] = tw[wave][74 + k];
        #pragma unroll
        for (int it = 0; it < 3; ++it) {
            int og = lane + it * 64;
            bool v = (og < 189);
            int y = v ? (og / 7) : 0;
            int xg = og - (og / 7) * 7;
            int x0 = xg * 4;
            float a0 = 0, a1 = 0, a2 = 0, a3 = 0;
            #pragma unroll
            for (int dy = 0; dy < 3; ++dy) {
                const float* rp = P + (y + 2 + dy) * 36 + x0;
                float4 fA = *(const float4*)rp;
                float4 fB = *(const float4*)(rp + 4);
                float f[8] = {fA.x, fA.y, fA.z, fA.w, fB.x, fB.y, fB.z, fB.w};
                #pragma unroll
                for (int dx = 0; dx < 3; ++dx) {
                    float t = t3[dy * 3 + dx];
                    a0 = fmaf(t, f[2 + dx], a0);
                    a1 = fmaf(t, f[3 + dx], a1);
                    a2 = fmaf(t, f[4 + dx], a2);
                    a3 = fmaf(t, f[5 + dx], a3);
                }
            }
            if (v) {
                size_t o = (size_t)bc * 729 + y * 27 + x0;
                sc[o] = a0;
                sc[o + 1] = a1;
                sc[o + 2] = a2;
                if (x0 + 3 < 27) sc[o + 3] = a3;
            }
        }
    }
}

// ---------------------------------------------------------------------------
// head v2 (R4-proven): sigmoid(w2 . relu(BN(W1.x+b1)) + b2), split-bf16 MFMA.
// grid (ceil(Np/128), 64)
// ---------------------------------------------------------------------------
__global__ __launch_bounds__(256) void head_mfma_kernel(
    const float* __restrict__ X,
    const float* __restrict__ w1,
    const float* __restrict__ b1,
    const float* __restrict__ g1, const float* __restrict__ be1,
    const float* __restrict__ m1, const float* __restrict__ v1,
    const float* __restrict__ w2, const float* __restrict__ b2,
    float* __restrict__ out,
    int Np)
{
    const int b  = blockIdx.y;
    const int p0 = blockIdx.x * 128;
    const int tid = threadIdx.x;
    const int wave = tid >> 6, lane = tid & 63;
    const int l15 = lane & 15, quad = lane >> 4;

    __shared__ __align__(16) short Ah[256 * 32], Al[256 * 32];
    __shared__ __align__(16) short Bh[128 * 40], Bl[128 * 40];
    __shared__ float red[128 * 17];

    floatx4 acc[4][8];
    #pragma unroll
    for (int m = 0; m < 4; ++m)
        #pragma unroll
        for (int n = 0; n < 8; ++n) acc[m][n] = (floatx4){0.f, 0.f, 0.f, 0.f};

    const int cp  = tid & 15;
    const int pxq = tid >> 4;

    for (int k0 = 0; k0 < 256; k0 += 32) {
        {
            const float* src = w1 + (size_t)tid * 256 + k0;
            uint32_t h[16], l[16];
            #pragma unroll
            for (int q = 0; q < 8; ++q) {
                float4 v4 = *(const float4*)(src + q * 4);
                uint32_t pa = pack_hilo(v4.x), pb = pack_hilo(v4.y);
                uint32_t pc = pack_hilo(v4.z), pd = pack_hilo(v4.w);
                h[q * 2]     = (pa >> 16) | (pb & 0xFFFF0000u);
                h[q * 2 + 1] = (pc >> 16) | (pd & 0xFFFF0000u);
                l[q * 2]     = (pa & 0xFFFFu) | (pb << 16);
                l[q * 2 + 1] = (pc & 0xFFFFu) | (pd << 16);
            }
            #pragma unroll
            for (int q = 0; q < 4; ++q) {
                uint4 uh; uh.x = h[q*4]; uh.y = h[q*4+1]; uh.z = h[q*4+2]; uh.w = h[q*4+3];
                uint4 ul; ul.x = l[q*4]; ul.y = l[q*4+1]; ul.z = l[q*4+2]; ul.w = l[q*4+3];
                *(uint4*)(Ah + tid * 32 + q * 8) = uh;
                *(uint4*)(Al + tid * 32 + q * 8) = ul;
            }
        }
        #pragma unroll
        for (int halfp = 0; halfp < 2; ++halfp) {
            int pxl = halfp * 64 + pxq * 4;
            int gp = p0 + pxl;
            const float* r0 = X + ((size_t)(b * 256) + k0 + 2 * cp) * Np + gp;
            const float* r1 = r0 + Np;
            #pragma unroll
            for (int j = 0; j < 4; ++j) {
                float u = (gp + j < Np) ? r0[j] : 0.0f;
                float v = (gp + j < Np) ? r1[j] : 0.0f;
                uint32_t hu = pack_hilo(u), hv = pack_hilo(v);
                int o = (pxl + j) * 40 + 2 * cp;
                *(uint32_t*)(Bh + o) = (hu >> 16) | (hv & 0xFFFF0000u);
                *(uint32_t*)(Bl + o) = (hu & 0xFFFFu) | (hv << 16);
            }
        }
        __syncthreads();
        short8 amh[4], aml[4];
        #pragma unroll
        for (int m = 0; m < 4; ++m) {
            int ao = (wave * 64 + m * 16 + l15) * 32 + quad * 8;
            amh[m] = *(const short8*)(Ah + ao);
            aml[m] = *(const short8*)(Al + ao);
        }
        #pragma unroll
        for (int n = 0; n < 8; ++n) {
            int bo = (n * 16 + l15) * 40 + quad * 8;
            short8 bh = *(const short8*)(Bh + bo);
            short8 bl = *(const short8*)(Bl + bo);
            #pragma unroll
            for (int m = 0; m < 4; ++m) {
                acc[m][n] = __builtin_amdgcn_mfma_f32_16x16x32_bf16(amh[m], bh, acc[m][n], 0, 0, 0);
                acc[m][n] = __builtin_amdgcn_mfma_f32_16x16x32_bf16(amh[m], bl, acc[m][n], 0, 0, 0);
                acc[m][n] = __builtin_amdgcn_mfma_f32_16x16x32_bf16(aml[m], bh, acc[m][n], 0, 0, 0);
            }
        }
        __syncthreads();
    }

    float Ac[16], Oc[16], Wc[16];
    #pragma unroll
    for (int m = 0; m < 4; ++m)
        #pragma unroll
        for (int reg = 0; reg < 4; ++reg) {
            int co = wave * 64 + m * 16 + quad * 4 + reg;
            float A = g1[co] * rsqrtf(v1[co] + 1e-5f);
            Ac[m * 4 + reg] = A;
            Oc[m * 4 + reg] = fmaf(b1[co] - m1[co], A, be1[co]);
            Wc[m * 4 + reg] = w2[co];
        }
    #pragma unroll
    for (int n = 0; n < 8; ++n) {
        float part = 0.0f;
        #pragma unroll
        for (int m = 0; m < 4; ++m)
            #pragma unroll
            for (int reg = 0; reg < 4; ++reg) {
                float y = fmaxf(fmaf(acc[m][n][reg], Ac[m * 4 + reg], Oc[m * 4 + reg]), 0.0f);
                part = fmaf(Wc[m * 4 + reg], y, part);
            }
        red[(n * 16 + l15) * 17 + wave * 4 + quad] = part;
    }
    __syncthreads();
    if (tid < 128) {
        float z = b2[0];
        #pragma unroll
        for (int k = 0; k < 16; ++k) z += red[tid * 17 + k];
        if (p0 + tid < Np)
            out[(size_t)b * Np + p0 + tid] = 1.0f / (1.0f + expf(-z));
    }
}

// ---------------------------------------------------------------------------
extern "C" void kernel_launch(void* const* d_in, const int* in_sizes, int n_in,
                              void* d_out, int out_size, void* d_ws, size_t ws_size,
                              hipStream_t stream)
{
    const float* large  = (const float*)d_in[0];
    const float* medium = (const float*)d_in[1];
    const float* small  = (const float*)d_in[2];
    const float* search = (const float*)d_in[3];
    const float* wt  = (const float*)d_in[4];
    const float* bt  = (const float*)d_in[5];
    const float* gt  = (const float*)d_in[6];
    const float* bet = (const float*)d_in[7];
    const float* mt  = (const float*)d_in[8];
    const float* vt  = (const float*)d_in[9];
    const float* wsc = (const float*)d_in[10];
    const float* bs  = (const float*)d_in[11];
    const float* gs  = (const float*)d_in[12];
    const float* bes = (const float*)d_in[13];
    const float* ms  = (const float*)d_in[14];
    const float* vs  = (const float*)d_in[15];
    const float* w1  = (const float*)d_in[16];
    const float* b1  = (const float*)d_in[17];
    const float* g1  = (const float*)d_in[18];
    const float* be1 = (const float*)d_in[19];
    const float* m1  = (const float*)d_in[20];
    const float* v1  = (const float*)d_in[21];
    const float* w2  = (const float*)d_in[22];
    const float* b2  = (const float*)d_in[23];

    float* ws = (float*)d_ws;
    size_t off = 0;
    float* lf = ws + off; off += (size_t)64 * 256 * 49;
    float* mf = ws + off; off += (size_t)64 * 256 * 25;
    float* sf = ws + off; off += (size_t)64 * 256 * 9;
    float* sq = ws + off; off += (size_t)64 * 256 * 841;
    float* lc = ws + off; off += (size_t)64 * 256 * 729;
    float* mc = ws + off; off += (size_t)64 * 256 * 625;
    float* sc = ws + off; off += (size_t)64 * 256 * 729;

    // Aliased prep buffers (dead before corr writes lc/mc/sc):
    short* xh_s = (short*)lc;
    short* xl_s = (short*)lc + 15745024;
    short* base = (short*)sc;
    short* xh_L = base;
    short* xl_L = base + 1327104;
    short* xh_M = base + 2654208;
    short* xl_M = base + 3457024;
    short* xh_S = base + 4259840;
    short* xl_S = base + 4669440;
    short* wh_t = base + 5079040;
    short* wl_t = base + 5668864;
    short* wh_s = base + 6258688;
    short* wl_s = base + 6848512;

    dim3 blk(256);
    prep_w_split<<<dim3(128), blk, 0, stream>>>(wt,  wh_t, wl_t);
    prep_w_split<<<dim3(128), blk, 0, stream>>>(wsc, wh_s, wl_s);
    prep_x_split<<<dim3(16, 4, 64), blk, 0, stream>>>(search, xh_s, xl_s, 961);
    prep_x_split<<<dim3(2, 4, 64),  blk, 0, stream>>>(large,  xh_L, xl_L, 81);
    prep_x_split<<<dim3(1, 4, 64),  blk, 0, stream>>>(medium, xh_M, xl_M, 49);
    prep_x_split<<<dim3(1, 4, 64),  blk, 0, stream>>>(small,  xh_S, xl_S, 25);

    conv_mfma_tmpl<<<dim3(2, 192), blk, 0, stream>>>(
        xh_L, xl_L, xh_M, xl_M, xh_S, xl_S, wh_t, wl_t,
        bt, gt, bet, mt, vt, lf, mf, sf);
    conv_mfma_search<<<dim3(7, 2, 64), blk, 0, stream>>>(
        xh_s, xl_s, wh_s, wl_s, bs, gs, bes, ms, vs, sq, 31, 31);

    corr_kernel<<<dim3(64, 64), blk, 0, stream>>>(lf, mf, sf, sq, lc, mc, sc);

    float* outp = (float*)d_out;
    head_mfma_kernel<<<dim3(6, 64), blk, 0, stream>>>(lc, w1, b1, g1, be1, m1, v1, w2, b2, outp, 729);
    head_mfma_kernel<<<dim3(5, 64), blk, 0, stream>>>(mc, w1, b1, g1, be1, m1, v1, w2, b2, outp + 46656, 625);
    head_mfma_kernel<<<dim3(6, 64), blk, 0, stream>>>(sc, w1, b1, g1, be1, m1, v1, w2, b2, outp + 86656, 729);
}

// Round 7
// 836.854 us; speedup vs baseline: 1.9832x; 1.1646x over previous
//
#include <hip/hip_runtime.h>
#include <math.h>
#include <stdint.h>

typedef __attribute__((ext_vector_type(8))) short short8;
typedef __attribute__((ext_vector_type(4))) float floatx4;

// fp32 -> (bf16 hi | bf16 lo) packed u32.  hi = RNE(x), lo = RNE(x - hi).
__device__ __forceinline__ uint32_t pack_hilo(float x) {
    uint32_t u = __float_as_uint(x);
    uint32_t hi = (u + 0x7FFFu + ((u >> 16) & 1u)) & 0xFFFF0000u;
    float r = x - __uint_as_float(hi);
    uint32_t v = __float_as_uint(r);
    uint32_t lo = ((v + 0x7FFFu + ((v >> 16) & 1u)) >> 16) & 0xFFFFu;
    return hi | lo;
}

// async global->LDS DMA, 16 B per lane; lds dest must be wave-uniform base.
__device__ __forceinline__ void dma16(short* lds, const short* g) {
    __builtin_amdgcn_global_load_lds(
        (const __attribute__((address_space(1))) unsigned int*)g,
        (__attribute__((address_space(3))) unsigned int*)lds,
        16, 0, 0);
}

// ---------------------------------------------------------------------------
// Prep: x (64,256,HW) fp32 -> xh,xl (64,HW,256) bf16 shorts (ci contiguous).
// ---------------------------------------------------------------------------
__global__ __launch_bounds__(256) void prep_x_split(
    const float* __restrict__ x, short* __restrict__ xh, short* __restrict__ xl,
    int HW)
{
    const int b = blockIdx.z, c0 = blockIdx.y * 64, p0 = blockIdx.x * 64;
    const int tid = threadIdx.x;
    const int a = tid & 63, g = tid >> 6;
    __shared__ uint32_t t[64][65];
    #pragma unroll
    for (int i = 0; i < 16; ++i) {
        int c = g + i * 4;
        int p = p0 + a;
        float v = (p < HW) ? x[((size_t)(b * 256) + c0 + c) * HW + p] : 0.0f;
        t[c][a] = pack_hilo(v);
    }
    __syncthreads();
    const int j = tid & 31;
    const int gg = tid >> 5;
    #pragma unroll
    for (int i = 0; i < 8; ++i) {
        int p = gg + i * 8;
        if (p0 + p < HW) {
            uint32_t w0 = t[2 * j][p], w1 = t[2 * j + 1][p];
            size_t o = ((size_t)b * HW + p0 + p) * 256 + c0 + 2 * j;
            *(uint32_t*)(xh + o) = (w0 >> 16) | (w1 & 0xFFFF0000u);
            *(uint32_t*)(xl + o) = (w0 & 0xFFFFu) | (w1 << 16);
        }
    }
}

// ---------------------------------------------------------------------------
// Prep: w (256,256,3,3) fp32 -> wh,wl (9,256co,256ci) bf16 shorts.
// ---------------------------------------------------------------------------
__global__ __launch_bounds__(256) void prep_w_split(
    const float* __restrict__ w, short* __restrict__ wh, short* __restrict__ wl)
{
    const int idx = blockIdx.x * 256 + threadIdx.x;
    const int co = idx >> 7, jp = idx & 127;
    const float* s0 = w + ((size_t)co * 256 + 2 * jp) * 9;
    #pragma unroll
    for (int r = 0; r < 9; ++r) {
        uint32_t q0 = pack_hilo(s0[r]);
        uint32_t q1 = pack_hilo(s0[9 + r]);
        size_t o = (size_t)r * 65536 + (size_t)co * 256 + 2 * jp;
        *(uint32_t*)(wh + o) = (q0 >> 16) | (q1 & 0xFFFF0000u);
        *(uint32_t*)(wl + o) = (q0 & 0xFFFFu) | (q1 << 16);
    }
}

// ===========================================================================
// MFMA conv body, async-DMA double-buffered.
// Block tile 128co x 128px, K = 9 taps x 256 ci in 72 chunks of 32 ci.
// Per chunk per wave: 8 global_load_lds_dwordx4 (1 KB each) into the next
// LDS buffer; manual s_waitcnt vmcnt(8) drains only the PREVIOUS chunk's
// DMAs, so global latency hides behind a full chunk of MFMA.
// smem layout: 2 buffers x [a_h|a_l|b_h|b_l] x 4096 shorts (64 KB total).
// ===========================================================================
__device__ __forceinline__ void conv_body(
    const short* __restrict__ xh, const short* __restrict__ xl,
    const short* __restrict__ wh, const short* __restrict__ wl,
    const float* __restrict__ bias,
    const float* __restrict__ gam, const float* __restrict__ bet,
    const float* __restrict__ mu,  const float* __restrict__ var,
    float* __restrict__ out,
    int b, int co0, int p0, int H, int W, short* smem)
{
    const int HW = H * W;
    const int Wo = W - 2, P = Wo * Wo;
    const int tid  = threadIdx.x;
    const int wave = tid >> 6, lane = tid & 63;
    const int l15  = lane & 15, quad = lane >> 4;

    int NT = (P - p0 + 15) >> 4;
    if (NT > 8) NT = 8;

    // per-lane DMA source bases (shorts). lane -> 16B slice: row lane>>2,
    // ci-quarter lane&3. Wave w covers rows [32w,32w+32), d in {0,1} = 16-row halves.
    const int lsub = lane >> 2;
    const int lq   = (lane & 3) * 8;
    const size_t abase0 = (size_t)(co0 + wave * 32 + lsub) * 256 + lq;
    const size_t abase1 = abase0 + 16 * 256;
    int pr0 = p0 + wave * 32 + lsub;      if (pr0 >= P) pr0 = 0;
    int pr1 = p0 + wave * 32 + 16 + lsub; if (pr1 >= P) pr1 = 0;
    const size_t bbase0 = ((size_t)b * HW + (pr0 / Wo) * W + (pr0 % Wo)) * 256 + lq;
    const size_t bbase1 = ((size_t)b * HW + (pr1 / Wo) * W + (pr1 % Wo)) * 256 + lq;

    const int ldsw = wave * 1024;  // wave's 2 KB region within a sub-buffer

    floatx4 acc[2][8];
    #pragma unroll
    for (int s = 0; s < 2; ++s)
        #pragma unroll
        for (int t = 0; t < 8; ++t) acc[s][t] = (floatx4){0.f, 0.f, 0.f, 0.f};

    const int fA = (wave * 32 + l15) * 32 + quad * 8;
    int fB[8];
    #pragma unroll
    for (int t = 0; t < 8; ++t) fB[t] = (t * 16 + l15) * 32 + quad * 8;

    // DMA issue for chunk k into buffer q
    auto issue = [&](int k, int q) {
        const int r = k >> 3, c4 = k & 7;
        const int ry = r / 3, rx = r - ry * 3;
        const size_t ga = (size_t)r * 65536 + c4 * 32;
        const size_t gb = (size_t)(ry * W + rx) * 256 + c4 * 32;
        short* base = smem + q * 16384;
        dma16(base + ldsw,                wh + ga + abase0);
        dma16(base + ldsw + 512,          wh + ga + abase1);
        dma16(base + 4096 + ldsw,         wl + ga + abase0);
        dma16(base + 4096 + ldsw + 512,   wl + ga + abase1);
        dma16(base + 8192 + ldsw,         xh + gb + bbase0);
        dma16(base + 8192 + ldsw + 512,   xh + gb + bbase1);
        dma16(base + 12288 + ldsw,        xl + gb + bbase0);
        dma16(base + 12288 + ldsw + 512,  xl + gb + bbase1);
    };

    issue(0, 0);
    for (int k = 0; k < 72; ++k) {
        const int q = k & 1;
        asm volatile("s_barrier" ::: "memory");          // prev buffer free
        if (k + 1 < 72) {
            issue(k + 1, q ^ 1);
            asm volatile("s_waitcnt vmcnt(8)" ::: "memory");  // chunk k landed
        } else {
            asm volatile("s_waitcnt vmcnt(0)" ::: "memory");
        }
        asm volatile("s_barrier" ::: "memory");          // chunk k visible to all
        const short* bq = smem + q * 16384;
        short8 a0h = *(const short8*)(bq + fA);
        short8 a1h = *(const short8*)(bq + fA + 512);
        short8 a0l = *(const short8*)(bq + 4096 + fA);
        short8 a1l = *(const short8*)(bq + 4096 + fA + 512);
        #pragma unroll
        for (int t = 0; t < 8; ++t) {
            if (t < NT) {
                short8 vh = *(const short8*)(bq + 8192 + fB[t]);
                short8 vl = *(const short8*)(bq + 12288 + fB[t]);
                acc[0][t] = __builtin_amdgcn_mfma_f32_16x16x32_bf16(a0h, vh, acc[0][t], 0, 0, 0);
                acc[1][t] = __builtin_amdgcn_mfma_f32_16x16x32_bf16(a1h, vh, acc[1][t], 0, 0, 0);
                acc[0][t] = __builtin_amdgcn_mfma_f32_16x16x32_bf16(a0h, vl, acc[0][t], 0, 0, 0);
                acc[1][t] = __builtin_amdgcn_mfma_f32_16x16x32_bf16(a1h, vl, acc[1][t], 0, 0, 0);
                acc[0][t] = __builtin_amdgcn_mfma_f32_16x16x32_bf16(a0l, vh, acc[0][t], 0, 0, 0);
                acc[1][t] = __builtin_amdgcn_mfma_f32_16x16x32_bf16(a1l, vh, acc[1][t], 0, 0, 0);
            }
        }
    }

    // epilogue: D layout col(px)=lane&15, row(co)=quad*4+reg  [verified m89/m91]
    #pragma unroll
    for (int s = 0; s < 2; ++s) {
        const int cobase = co0 + wave * 32 + s * 16 + quad * 4;
        #pragma unroll
        for (int reg = 0; reg < 4; ++reg) {
            const int co = cobase + reg;
            const float A   = gam[co] * rsqrtf(var[co] + 1e-5f);
            const float OFF = fmaf(bias[co] - mu[co], A, bet[co]);
            float* orow = out + ((size_t)(b * 256 + co)) * P;
            #pragma unroll
            for (int t = 0; t < 8; ++t) {
                int px = p0 + t * 16 + l15;
                if (px < P)
                    orow[px] = fmaxf(fmaf(acc[s][t][reg], A, OFF), 0.0f);
            }
        }
    }
}

// ---------------------------------------------------------------------------
// conv_search: 1-D grid 896 with XCD-aware swizzle — all 14 tiles (7 px-blocks
// x 2 co-halves) of one batch sample land on the same XCD (assuming round-
// robin block->XCD), so its ~1 MB of activations stays in that XCD's 4MB L2.
// ---------------------------------------------------------------------------
__global__ __launch_bounds__(256) void conv_mfma_search(
    const short* __restrict__ xh, const short* __restrict__ xl,
    const short* __restrict__ wh, const short* __restrict__ wl,
    const float* __restrict__ bias,
    const float* __restrict__ gam, const float* __restrict__ bet,
    const float* __restrict__ mu,  const float* __restrict__ var,
    float* __restrict__ out)
{
    __shared__ __align__(16) short smem[32768];
    const int i = blockIdx.x;           // 0..895
    const int xcd = i & 7, slot = i >> 3;   // 112 slots per xcd = 8 b x 14 tiles
    const int bl = slot / 14, tile = slot - bl * 14;
    const int b = xcd * 8 + bl;
    conv_body(xh, xl, wh, wl, bias, gam, bet, mu, var, out,
              b, (tile & 1) * 128, (tile >> 1) * 128, 31, 31, smem);
}

// ---------------------------------------------------------------------------
// conv_tmpl: all 3 template scales in one dispatch. grid (2, 192):
// blockIdx.x = co half, blockIdx.y = scale*64 + b.
// ---------------------------------------------------------------------------
__global__ __launch_bounds__(256) void conv_mfma_tmpl(
    const short* __restrict__ xhL, const short* __restrict__ xlL,
    const short* __restrict__ xhM, const short* __restrict__ xlM,
    const short* __restrict__ xhS, const short* __restrict__ xlS,
    const short* __restrict__ wh,  const short* __restrict__ wl,
    const float* __restrict__ bias,
    const float* __restrict__ gam, const float* __restrict__ bet,
    const float* __restrict__ mu,  const float* __restrict__ var,
    float* __restrict__ outL, float* __restrict__ outM, float* __restrict__ outS)
{
    __shared__ __align__(16) short smem[32768];
    const int sb = blockIdx.y;
    const int scale = sb >> 6, b = sb & 63;
    const short* xh = (scale == 0) ? xhL : (scale == 1) ? xhM : xhS;
    const short* xl = (scale == 0) ? xlL : (scale == 1) ? xlM : xlS;
    float* out      = (scale == 0) ? outL : (scale == 1) ? outM : outS;
    const int H     = (scale == 0) ? 9 : (scale == 1) ? 7 : 5;
    conv_body(xh, xl, wh, wl, bias, gam, bet, mu, var, out,
              b, blockIdx.x * 128, 0, H, H, smem);
}

// ---------------------------------------------------------------------------
// corr v2 (R4-proven): one wave per (b,c); templates in VGPRs; 4-wide outputs
// with b128 sliding-window reads from a padded 33x36 LDS plane. grid (64,64)
// ---------------------------------------------------------------------------
__global__ __launch_bounds__(256) void corr_kernel(
    const float* __restrict__ lf, const float* __restrict__ mf,
    const float* __restrict__ sf, const float* __restrict__ s,
    float* __restrict__ lc, float* __restrict__ mc, float* __restrict__ sc)
{
    const int b = blockIdx.y;
    const int wave = threadIdx.x >> 6, lane = threadIdx.x & 63;
    const int c = blockIdx.x * 4 + wave;
    const int bc = b * 256 + c;

    __shared__ __align__(16) float sp[4][33 * 36];
    __shared__ float tw[4][96];

    float* P = sp[wave];
    for (int i = lane; i < 33 * 36; i += 64) P[i] = 0.0f;
    if (lane < 49) tw[wave][lane]      = lf[(size_t)bc * 49 + lane];
    if (lane < 25) tw[wave][49 + lane] = mf[(size_t)bc * 25 + lane];
    if (lane < 9)  tw[wave][74 + lane] = sf[(size_t)bc * 9 + lane];
    for (int i = lane; i < 841; i += 64) {
        int y = i / 29, x = i - y * 29;
        P[(y + 2) * 36 + (x + 2)] = s[(size_t)bc * 841 + i];
    }
    __syncthreads();

    {
        float t7[49];
        #pragma unroll
        for (int k = 0; k < 49; ++k) t7[k] = tw[wave][k];
        #pragma unroll
        for (int it = 0; it < 3; ++it) {
            int og = lane + it * 64;
            bool v = (og < 189);
            int y = v ? (og / 7) : 0;
            int xg = og - (og / 7) * 7;
            int x0 = xg * 4;
            float a0 = 0, a1 = 0, a2 = 0, a3 = 0;
            #pragma unroll
            for (int dy = 0; dy < 7; ++dy) {
                const float* rp = P + (y + dy) * 36 + x0;
                float4 fA = *(const float4*)rp;
                float4 fB = *(const float4*)(rp + 4);
                float4 fC = *(const float4*)(rp + 8);
                float f[12] = {fA.x, fA.y, fA.z, fA.w, fB.x, fB.y, fB.z, fB.w,
                               fC.x, fC.y, fC.z, fC.w};
                #pragma unroll
                for (int dx = 0; dx < 7; ++dx) {
                    float t = t7[dy * 7 + dx];
                    a0 = fmaf(t, f[dx], a0);
                    a1 = fmaf(t, f[dx + 1], a1);
                    a2 = fmaf(t, f[dx + 2], a2);
                    a3 = fmaf(t, f[dx + 3], a3);
                }
            }
            if (v) {
                size_t o = (size_t)bc * 729 + y * 27 + x0;
                lc[o] = a0;
                lc[o + 1] = a1;
                lc[o + 2] = a2;
                if (x0 + 3 < 27) lc[o + 3] = a3;
            }
        }
    }
    {
        float t5[25];
        #pragma unroll
        for (int k = 0; k < 25; ++k) t5[k] = tw[wave][49 + k];
        #pragma unroll
        for (int it = 0; it < 3; ++it) {
            int og = lane + it * 64;
            bool v = (og < 175);
            int y = v ? (og / 7) : 0;
            int xg = og - (og / 7) * 7;
            int x0 = xg * 4;
            float a0 = 0, a1 = 0, a2 = 0, a3 = 0;
            #pragma unroll
            for (int dy = 0; dy < 5; ++dy) {
                const float* rp = P + (y + 2 + dy) * 36 + x0;
                float4 fA = *(const float4*)rp;
                float4 fB = *(const float4*)(rp + 4);
                float4 fC = *(const float4*)(rp + 8);
                float f[12] = {fA.x, fA.y, fA.z, fA.w, fB.x, fB.y, fB.z, fB.w,
                               fC.x, fC.y, fC.z, fC.w};
                #pragma unroll
                for (int dx = 0; dx < 5; ++dx) {
                    float t = t5[dy * 5 + dx];
                    a0 = fmaf(t, f[2 + dx], a0);
                    a1 = fmaf(t, f[3 + dx], a1);
                    a2 = fmaf(t, f[4 + dx], a2);
                    a3 = fmaf(t, f[5 + dx], a3);
                }
            }
            if (v) {
                size_t o = (size_t)bc * 625 + y * 25 + x0;
                mc[o] = a0;
                if (x0 + 1 < 25) mc[o + 1] = a1;
                if (x0 + 2 < 25) mc[o + 2] = a2;
                if (x0 + 3 < 25) mc[o + 3] = a3;
            }
        }
    }
    {
        float t3[9];
        #pragma unroll
        for (int k = 0; k < 9; ++k) t3[k] = tw[wave][74 + k];
        #pragma unroll
        for (int it = 0; it < 3; ++it) {
            int og = lane + it * 64;
            bool v = (og < 189);
            int y = v ? (og / 7) : 0;
            int xg = og - (og / 7) * 7;
            int x0 = xg * 4;
            float a0 = 0, a1 = 0, a2 = 0, a3 = 0;
            #pragma unroll
            for (int dy = 0; dy < 3; ++dy) {
                const float* rp = P + (y + 2 + dy) * 36 + x0;
                float4 fA = *(const float4*)rp;
                float4 fB = *(const float4*)(rp + 4);
                float f[8] = {fA.x, fA.y, fA.z, fA.w, fB.x, fB.y, fB.z, fB.w};
                #pragma unroll
                for (int dx = 0; dx < 3; ++dx) {
                    float t = t3[dy * 3 + dx];
                    a0 = fmaf(t, f[2 + dx], a0);
                    a1 = fmaf(t, f[3 + dx], a1);
                    a2 = fmaf(t, f[4 + dx], a2);
                    a3 = fmaf(t, f[5 + dx], a3);
                }
            }
            if (v) {
                size_t o = (size_t)bc * 729 + y * 27 + x0;
                sc[o] = a0;
                sc[o + 1] = a1;
                sc[o + 2] = a2;
                if (x0 + 3 < 27) sc[o + 3] = a3;
            }
        }
    }
}

// ---------------------------------------------------------------------------
// head v2 (R4-proven): sigmoid(w2 . relu(BN(W1.x+b1)) + b2), split-bf16 MFMA.
// grid (ceil(Np/128), 64)
// ---------------------------------------------------------------------------
__global__ __launch_bounds__(256) void head_mfma_kernel(
    const float* __restrict__ X,
    const float* __restrict__ w1,
    const float* __restrict__ b1,
    const float* __restrict__ g1, const float* __restrict__ be1,
    const float* __restrict__ m1, const float* __restrict__ v1,
    const float* __restrict__ w2, const float* __restrict__ b2,
    float* __restrict__ out,
    int Np)
{
    const int b  = blockIdx.y;
    const int p0 = blockIdx.x * 128;
    const int tid = threadIdx.x;
    const int wave = tid >> 6, lane = tid & 63;
    const int l15 = lane & 15, quad = lane >> 4;

    __shared__ __align__(16) short Ah[256 * 32], Al[256 * 32];
    __shared__ __align__(16) short Bh[128 * 40], Bl[128 * 40];
    __shared__ float red[128 * 17];

    floatx4 acc[4][8];
    #pragma unroll
    for (int m = 0; m < 4; ++m)
        #pragma unroll
        for (int n = 0; n < 8; ++n) acc[m][n] = (floatx4){0.f, 0.f, 0.f, 0.f};

    const int cp  = tid & 15;
    const int pxq = tid >> 4;

    for (int k0 = 0; k0 < 256; k0 += 32) {
        {
            const float* src = w1 + (size_t)tid * 256 + k0;
            uint32_t h[16], l[16];
            #pragma unroll
            for (int q = 0; q < 8; ++q) {
                float4 v4 = *(const float4*)(src + q * 4);
                uint32_t pa = pack_hilo(v4.x), pb = pack_hilo(v4.y);
                uint32_t pc = pack_hilo(v4.z), pd = pack_hilo(v4.w);
                h[q * 2]     = (pa >> 16) | (pb & 0xFFFF0000u);
                h[q * 2 + 1] = (pc >> 16) | (pd & 0xFFFF0000u);
                l[q * 2]     = (pa & 0xFFFFu) | (pb << 16);
                l[q * 2 + 1] = (pc & 0xFFFFu) | (pd << 16);
            }
            #pragma unroll
            for (int q = 0; q < 4; ++q) {
                uint4 uh; uh.x = h[q*4]; uh.y = h[q*4+1]; uh.z = h[q*4+2]; uh.w = h[q*4+3];
                uint4 ul; ul.x = l[q*4]; ul.y = l[q*4+1]; ul.z = l[q*4+2]; ul.w = l[q*4+3];
                *(uint4*)(Ah + tid * 32 + q * 8) = uh;
                *(uint4*)(Al + tid * 32 + q * 8) = ul;
            }
        }
        #pragma unroll
        for (int halfp = 0; halfp < 2; ++halfp) {
            int pxl = halfp * 64 + pxq * 4;
            int gp = p0 + pxl;
            const float* r0 = X + ((size_t)(b * 256) + k0 + 2 * cp) * Np + gp;
            const float* r1 = r0 + Np;
            #pragma unroll
            for (int j = 0; j < 4; ++j) {
                float u = (gp + j < Np) ? r0[j] : 0.0f;
                float v = (gp + j < Np) ? r1[j] : 0.0f;
                uint32_t hu = pack_hilo(u), hv = pack_hilo(v);
                int o = (pxl + j) * 40 + 2 * cp;
                *(uint32_t*)(Bh + o) = (hu >> 16) | (hv & 0xFFFF0000u);
                *(uint32_t*)(Bl + o) = (hu & 0xFFFFu) | (hv << 16);
            }
        }
        __syncthreads();
        short8 amh[4], aml[4];
        #pragma unroll
        for (int m = 0; m < 4; ++m) {
            int ao = (wave * 64 + m * 16 + l15) * 32 + quad * 8;
            amh[m] = *(const short8*)(Ah + ao);
            aml[m] = *(const short8*)(Al + ao);
        }
        #pragma unroll
        for (int n = 0; n < 8; ++n) {
            int bo = (n * 16 + l15) * 40 + quad * 8;
            short8 bh = *(const short8*)(Bh + bo);
            short8 bl = *(const short8*)(Bl + bo);
            #pragma unroll
            for (int m = 0; m < 4; ++m) {
                acc[m][n] = __builtin_amdgcn_mfma_f32_16x16x32_bf16(amh[m], bh, acc[m][n], 0, 0, 0);
                acc[m][n] = __builtin_amdgcn_mfma_f32_16x16x32_bf16(amh[m], bl, acc[m][n], 0, 0, 0);
                acc[m][n] = __builtin_amdgcn_mfma_f32_16x16x32_bf16(aml[m], bh, acc[m][n], 0, 0, 0);
            }
        }
        __syncthreads();
    }

    float Ac[16], Oc[16], Wc[16];
    #pragma unroll
    for (int m = 0; m < 4; ++m)
        #pragma unroll
        for (int reg = 0; reg < 4; ++reg) {
            int co = wave * 64 + m * 16 + quad * 4 + reg;
            float A = g1[co] * rsqrtf(v1[co] + 1e-5f);
            Ac[m * 4 + reg] = A;
            Oc[m * 4 + reg] = fmaf(b1[co] - m1[co], A, be1[co]);
            Wc[m * 4 + reg] = w2[co];
        }
    #pragma unroll
    for (int n = 0; n < 8; ++n) {
        float part = 0.0f;
        #pragma unroll
        for (int m = 0; m < 4; ++m)
            #pragma unroll
            for (int reg = 0; reg < 4; ++reg) {
                float y = fmaxf(fmaf(acc[m][n][reg], Ac[m * 4 + reg], Oc[m * 4 + reg]), 0.0f);
                part = fmaf(Wc[m * 4 + reg], y, part);
            }
        red[(n * 16 + l15) * 17 + wave * 4 + quad] = part;
    }
    __syncthreads();
    if (tid < 128) {
        float z = b2[0];
        #pragma unroll
        for (int k = 0; k < 16; ++k) z += red[tid * 17 + k];
        if (p0 + tid < Np)
            out[(size_t)b * Np + p0 + tid] = 1.0f / (1.0f + expf(-z));
    }
}

// ---------------------------------------------------------------------------
extern "C" void kernel_launch(void* const* d_in, const int* in_sizes, int n_in,
                              void* d_out, int out_size, void* d_ws, size_t ws_size,
                              hipStream_t stream)
{
    const float* large  = (const float*)d_in[0];
    const float* medium = (const float*)d_in[1];
    const float* small  = (const float*)d_in[2];
    const float* search = (const float*)d_in[3];
    const float* wt  = (const float*)d_in[4];
    const float* bt  = (const float*)d_in[5];
    const float* gt  = (const float*)d_in[6];
    const float* bet = (const float*)d_in[7];
    const float* mt  = (const float*)d_in[8];
    const float* vt  = (const float*)d_in[9];
    const float* wsc = (const float*)d_in[10];
    const float* bs  = (const float*)d_in[11];
    const float* gs  = (const float*)d_in[12];
    const float* bes = (const float*)d_in[13];
    const float* ms  = (const float*)d_in[14];
    const float* vs  = (const float*)d_in[15];
    const float* w1  = (const float*)d_in[16];
    const float* b1  = (const float*)d_in[17];
    const float* g1  = (const float*)d_in[18];
    const float* be1 = (const float*)d_in[19];
    const float* m1  = (const float*)d_in[20];
    const float* v1  = (const float*)d_in[21];
    const float* w2  = (const float*)d_in[22];
    const float* b2  = (const float*)d_in[23];

    float* ws = (float*)d_ws;
    size_t off = 0;
    float* lf = ws + off; off += (size_t)64 * 256 * 49;
    float* mf = ws + off; off += (size_t)64 * 256 * 25;
    float* sf = ws + off; off += (size_t)64 * 256 * 9;
    float* sq = ws + off; off += (size_t)64 * 256 * 841;
    float* lc = ws + off; off += (size_t)64 * 256 * 729;
    float* mc = ws + off; off += (size_t)64 * 256 * 625;
    float* sc = ws + off; off += (size_t)64 * 256 * 729;

    // Aliased prep buffers (dead before corr writes lc/mc/sc):
    short* xh_s = (short*)lc;
    short* xl_s = (short*)lc + 15745024;
    short* base = (short*)sc;
    short* xh_L = base;
    short* xl_L = base + 1327104;
    short* xh_M = base + 2654208;
    short* xl_M = base + 3457024;
    short* xh_S = base + 4259840;
    short* xl_S = base + 4669440;
    short* wh_t = base + 5079040;
    short* wl_t = base + 5668864;
    short* wh_s = base + 6258688;
    short* wl_s = base + 6848512;

    dim3 blk(256);
    prep_w_split<<<dim3(128), blk, 0, stream>>>(wt,  wh_t, wl_t);
    prep_w_split<<<dim3(128), blk, 0, stream>>>(wsc, wh_s, wl_s);
    prep_x_split<<<dim3(16, 4, 64), blk, 0, stream>>>(search, xh_s, xl_s, 961);
    prep_x_split<<<dim3(2, 4, 64),  blk, 0, stream>>>(large,  xh_L, xl_L, 81);
    prep_x_split<<<dim3(1, 4, 64),  blk, 0, stream>>>(medium, xh_M, xl_M, 49);
    prep_x_split<<<dim3(1, 4, 64),  blk, 0, stream>>>(small,  xh_S, xl_S, 25);

    conv_mfma_tmpl<<<dim3(2, 192), blk, 0, stream>>>(
        xh_L, xl_L, xh_M, xl_M, xh_S, xl_S, wh_t, wl_t,
        bt, gt, bet, mt, vt, lf, mf, sf);
    conv_mfma_search<<<dim3(896), blk, 0, stream>>>(
        xh_s, xl_s, wh_s, wl_s, bs, gs, bes, ms, vs, sq);

    corr_kernel<<<dim3(64, 64), blk, 0, stream>>>(lf, mf, sf, sq, lc, mc, sc);

    float* outp = (float*)d_out;
    head_mfma_kernel<<<dim3(6, 64), blk, 0, stream>>>(lc, w1, b1, g1, be1, m1, v1, w2, b2, outp, 729);
    head_mfma_kernel<<<dim3(5, 64), blk, 0, stream>>>(mc, w1, b1, g1, be1, m1, v1, w2, b2, outp + 46656, 625);
    head_mfma_kernel<<<dim3(6, 64), blk, 0, stream>>>(sc, w1, b1, g1, be1, m1, v1, w2, b2, outp + 86656, 729);
}

// Round 8
// 764.609 us; speedup vs baseline: 2.1706x; 1.0945x over previous
//
#include <hip/hip_runtime.h>
#include <math.h>
#include <stdint.h>

typedef __attribute__((ext_vector_type(8))) short short8;
typedef __attribute__((ext_vector_type(4))) float floatx4;

// fp32 -> (bf16 hi | bf16 lo) packed u32.  hi = RNE(x), lo = RNE(x - hi).
__device__ __forceinline__ uint32_t pack_hilo(float x) {
    uint32_t u = __float_as_uint(x);
    uint32_t hi = (u + 0x7FFFu + ((u >> 16) & 1u)) & 0xFFFF0000u;
    float r = x - __uint_as_float(hi);
    uint32_t v = __float_as_uint(r);
    uint32_t lo = ((v + 0x7FFFu + ((v >> 16) & 1u)) >> 16) & 0xFFFFu;
    return hi | lo;
}

// async global->LDS DMA, 16 B per lane; lds dest must be wave-uniform base.
__device__ __forceinline__ void dma16(short* lds, const short* g) {
    __builtin_amdgcn_global_load_lds(
        (const __attribute__((address_space(1))) unsigned int*)g,
        (__attribute__((address_space(3))) unsigned int*)lds,
        16, 0, 0);
}

// ---------------------------------------------------------------------------
// Fused prep: all four activation tensors -> hi/lo split, one dispatch.
// grid (20, 4, 64): bx 0..15 search(961), 16..17 large(81), 18 med(49), 19 small(25)
// ---------------------------------------------------------------------------
__global__ __launch_bounds__(256) void prep_x_all(
    const float* __restrict__ xs, short* __restrict__ xhS, short* __restrict__ xlS,
    const float* __restrict__ xL, short* __restrict__ xhL, short* __restrict__ xlL,
    const float* __restrict__ xM, short* __restrict__ xhM, short* __restrict__ xlM,
    const float* __restrict__ xSm, short* __restrict__ xhSm, short* __restrict__ xlSm)
{
    const int bx = blockIdx.x;
    const float* x; short *xh, *xl; int HW, p0;
    if (bx < 16)      { x = xs;  xh = xhS;  xl = xlS;  HW = 961; p0 = bx * 64; }
    else if (bx < 18) { x = xL;  xh = xhL;  xl = xlL;  HW = 81;  p0 = (bx - 16) * 64; }
    else if (bx < 19) { x = xM;  xh = xhM;  xl = xlM;  HW = 49;  p0 = 0; }
    else              { x = xSm; xh = xhSm; xl = xlSm; HW = 25;  p0 = 0; }

    const int b = blockIdx.z, c0 = blockIdx.y * 64;
    const int tid = threadIdx.x;
    const int a = tid & 63, g = tid >> 6;
    __shared__ uint32_t t[64][65];
    #pragma unroll
    for (int i = 0; i < 16; ++i) {
        int c = g + i * 4;
        int p = p0 + a;
        float v = (p < HW) ? x[((size_t)(b * 256) + c0 + c) * HW + p] : 0.0f;
        t[c][a] = pack_hilo(v);
    }
    __syncthreads();
    const int j = tid & 31;
    const int gg = tid >> 5;
    #pragma unroll
    for (int i = 0; i < 8; ++i) {
        int p = gg + i * 8;
        if (p0 + p < HW) {
            uint32_t w0 = t[2 * j][p], w1 = t[2 * j + 1][p];
            size_t o = ((size_t)b * HW + p0 + p) * 256 + c0 + 2 * j;
            *(uint32_t*)(xh + o) = (w0 >> 16) | (w1 & 0xFFFF0000u);
            *(uint32_t*)(xl + o) = (w0 & 0xFFFFu) | (w1 << 16);
        }
    }
}

// ---------------------------------------------------------------------------
// Prep both conv weights: bx<128 -> wt, else wsc. grid (256)
// ---------------------------------------------------------------------------
__global__ __launch_bounds__(256) void prep_w_both(
    const float* __restrict__ wA, short* __restrict__ whA, short* __restrict__ wlA,
    const float* __restrict__ wB, short* __restrict__ whB, short* __restrict__ wlB)
{
    int bx = blockIdx.x;
    const float* w; short *wh, *wl;
    if (bx < 128) { w = wA; wh = whA; wl = wlA; }
    else          { w = wB; wh = whB; wl = wlB; bx -= 128; }
    const int idx = bx * 256 + threadIdx.x;
    const int co = idx >> 7, jp = idx & 127;
    const float* s0 = w + ((size_t)co * 256 + 2 * jp) * 9;
    #pragma unroll
    for (int r = 0; r < 9; ++r) {
        uint32_t q0 = pack_hilo(s0[r]);
        uint32_t q1 = pack_hilo(s0[9 + r]);
        size_t o = (size_t)r * 65536 + (size_t)co * 256 + 2 * jp;
        *(uint32_t*)(wh + o) = (q0 >> 16) | (q1 & 0xFFFF0000u);
        *(uint32_t*)(wl + o) = (q0 & 0xFFFFu) | (q1 << 16);
    }
}

// ---------------------------------------------------------------------------
// Prep w1 (256,256) fp32 -> chunk-major hi/lo: w1hT[k][co][ci&31], k=ci>>5.
// grid (64) x 256 thr x 4 elems.  Launched AFTER corr (lives in dead sq).
// ---------------------------------------------------------------------------
__global__ __launch_bounds__(256) void prep_w1(
    const float* __restrict__ w1, short* __restrict__ w1hT, short* __restrict__ w1lT)
{
    const int idx = (blockIdx.x * 256 + threadIdx.x) * 4;
    const int co = idx >> 8, ci = idx & 255;
    const int pos = (ci >> 5) * 8192 + co * 32 + (ci & 31);
    float4 v4 = *(const float4*)(w1 + (size_t)co * 256 + ci);
    uint32_t pa = pack_hilo(v4.x), pb = pack_hilo(v4.y);
    uint32_t pc = pack_hilo(v4.z), pd = pack_hilo(v4.w);
    uint2 uh, ul;
    uh.x = (pa >> 16) | (pb & 0xFFFF0000u);
    uh.y = (pc >> 16) | (pd & 0xFFFF0000u);
    ul.x = (pa & 0xFFFFu) | (pb << 16);
    ul.y = (pc & 0xFFFFu) | (pd << 16);
    *(uint2*)(w1hT + pos) = uh;
    *(uint2*)(w1lT + pos) = ul;
}

// ===========================================================================
// MFMA conv body, async-DMA double-buffered (R7-proven).
// ===========================================================================
__device__ __forceinline__ void conv_body(
    const short* __restrict__ xh, const short* __restrict__ xl,
    const short* __restrict__ wh, const short* __restrict__ wl,
    const float* __restrict__ bias,
    const float* __restrict__ gam, const float* __restrict__ bet,
    const float* __restrict__ mu,  const float* __restrict__ var,
    float* __restrict__ out,
    int b, int co0, int p0, int H, int W, short* smem)
{
    const int HW = H * W;
    const int Wo = W - 2, P = Wo * Wo;
    const int tid  = threadIdx.x;
    const int wave = tid >> 6, lane = tid & 63;
    const int l15  = lane & 15, quad = lane >> 4;

    int NT = (P - p0 + 15) >> 4;
    if (NT > 8) NT = 8;

    const int lsub = lane >> 2;
    const int lq   = (lane & 3) * 8;
    const size_t abase0 = (size_t)(co0 + wave * 32 + lsub) * 256 + lq;
    const size_t abase1 = abase0 + 16 * 256;
    int pr0 = p0 + wave * 32 + lsub;      if (pr0 >= P) pr0 = 0;
    int pr1 = p0 + wave * 32 + 16 + lsub; if (pr1 >= P) pr1 = 0;
    const size_t bbase0 = ((size_t)b * HW + (pr0 / Wo) * W + (pr0 % Wo)) * 256 + lq;
    const size_t bbase1 = ((size_t)b * HW + (pr1 / Wo) * W + (pr1 % Wo)) * 256 + lq;

    const int ldsw = wave * 1024;

    floatx4 acc[2][8];
    #pragma unroll
    for (int s = 0; s < 2; ++s)
        #pragma unroll
        for (int t = 0; t < 8; ++t) acc[s][t] = (floatx4){0.f, 0.f, 0.f, 0.f};

    const int fA = (wave * 32 + l15) * 32 + quad * 8;
    int fB[8];
    #pragma unroll
    for (int t = 0; t < 8; ++t) fB[t] = (t * 16 + l15) * 32 + quad * 8;

    auto issue = [&](int k, int q) {
        const int r = k >> 3, c4 = k & 7;
        const int ry = r / 3, rx = r - ry * 3;
        const size_t ga = (size_t)r * 65536 + c4 * 32;
        const size_t gb = (size_t)(ry * W + rx) * 256 + c4 * 32;
        short* base = smem + q * 16384;
        dma16(base + ldsw,                wh + ga + abase0);
        dma16(base + ldsw + 512,          wh + ga + abase1);
        dma16(base + 4096 + ldsw,         wl + ga + abase0);
        dma16(base + 4096 + ldsw + 512,   wl + ga + abase1);
        dma16(base + 8192 + ldsw,         xh + gb + bbase0);
        dma16(base + 8192 + ldsw + 512,   xh + gb + bbase1);
        dma16(base + 12288 + ldsw,        xl + gb + bbase0);
        dma16(base + 12288 + ldsw + 512,  xl + gb + bbase1);
    };

    issue(0, 0);
    for (int k = 0; k < 72; ++k) {
        const int q = k & 1;
        asm volatile("s_barrier" ::: "memory");
        if (k + 1 < 72) {
            issue(k + 1, q ^ 1);
            asm volatile("s_waitcnt vmcnt(8)" ::: "memory");
        } else {
            asm volatile("s_waitcnt vmcnt(0)" ::: "memory");
        }
        asm volatile("s_barrier" ::: "memory");
        const short* bq = smem + q * 16384;
        short8 a0h = *(const short8*)(bq + fA);
        short8 a1h = *(const short8*)(bq + fA + 512);
        short8 a0l = *(const short8*)(bq + 4096 + fA);
        short8 a1l = *(const short8*)(bq + 4096 + fA + 512);
        #pragma unroll
        for (int t = 0; t < 8; ++t) {
            if (t < NT) {
                short8 vh = *(const short8*)(bq + 8192 + fB[t]);
                short8 vl = *(const short8*)(bq + 12288 + fB[t]);
                acc[0][t] = __builtin_amdgcn_mfma_f32_16x16x32_bf16(a0h, vh, acc[0][t], 0, 0, 0);
                acc[1][t] = __builtin_amdgcn_mfma_f32_16x16x32_bf16(a1h, vh, acc[1][t], 0, 0, 0);
                acc[0][t] = __builtin_amdgcn_mfma_f32_16x16x32_bf16(a0h, vl, acc[0][t], 0, 0, 0);
                acc[1][t] = __builtin_amdgcn_mfma_f32_16x16x32_bf16(a1h, vl, acc[1][t], 0, 0, 0);
                acc[0][t] = __builtin_amdgcn_mfma_f32_16x16x32_bf16(a0l, vh, acc[0][t], 0, 0, 0);
                acc[1][t] = __builtin_amdgcn_mfma_f32_16x16x32_bf16(a1l, vh, acc[1][t], 0, 0, 0);
            }
        }
    }

    #pragma unroll
    for (int s = 0; s < 2; ++s) {
        const int cobase = co0 + wave * 32 + s * 16 + quad * 4;
        #pragma unroll
        for (int reg = 0; reg < 4; ++reg) {
            const int co = cobase + reg;
            const float A   = gam[co] * rsqrtf(var[co] + 1e-5f);
            const float OFF = fmaf(bias[co] - mu[co], A, bet[co]);
            float* orow = out + ((size_t)(b * 256 + co)) * P;
            #pragma unroll
            for (int t = 0; t < 8; ++t) {
                int px = p0 + t * 16 + l15;
                if (px < P)
                    orow[px] = fmaxf(fmaf(acc[s][t][reg], A, OFF), 0.0f);
            }
        }
    }
}

// ---------------------------------------------------------------------------
// conv_search: 1-D grid 896, XCD-aware swizzle (R7-proven).
// ---------------------------------------------------------------------------
__global__ __launch_bounds__(256) void conv_mfma_search(
    const short* __restrict__ xh, const short* __restrict__ xl,
    const short* __restrict__ wh, const short* __restrict__ wl,
    const float* __restrict__ bias,
    const float* __restrict__ gam, const float* __restrict__ bet,
    const float* __restrict__ mu,  const float* __restrict__ var,
    float* __restrict__ out)
{
    __shared__ __align__(16) short smem[32768];
    const int i = blockIdx.x;
    const int xcd = i & 7, slot = i >> 3;
    const int bl = slot / 14, tile = slot - bl * 14;
    const int b = xcd * 8 + bl;
    conv_body(xh, xl, wh, wl, bias, gam, bet, mu, var, out,
              b, (tile & 1) * 128, (tile >> 1) * 128, 31, 31, smem);
}

// ---------------------------------------------------------------------------
// conv_tmpl: 3 template scales, one dispatch. grid (2, 192).
// ---------------------------------------------------------------------------
__global__ __launch_bounds__(256) void conv_mfma_tmpl(
    const short* __restrict__ xhL, const short* __restrict__ xlL,
    const short* __restrict__ xhM, const short* __restrict__ xlM,
    const short* __restrict__ xhS, const short* __restrict__ xlS,
    const short* __restrict__ wh,  const short* __restrict__ wl,
    const float* __restrict__ bias,
    const float* __restrict__ gam, const float* __restrict__ bet,
    const float* __restrict__ mu,  const float* __restrict__ var,
    float* __restrict__ outL, float* __restrict__ outM, float* __restrict__ outS)
{
    __shared__ __align__(16) short smem[32768];
    const int sb = blockIdx.y;
    const int scale = sb >> 6, b = sb & 63;
    const short* xh = (scale == 0) ? xhL : (scale == 1) ? xhM : xhS;
    const short* xl = (scale == 0) ? xlL : (scale == 1) ? xlM : xlS;
    float* out      = (scale == 0) ? outL : (scale == 1) ? outM : outS;
    const int H     = (scale == 0) ? 9 : (scale == 1) ? 7 : 5;
    conv_body(xh, xl, wh, wl, bias, gam, bet, mu, var, out,
              b, blockIdx.x * 128, 0, H, H, smem);
}

// ---------------------------------------------------------------------------
// corr v2 (R4-proven). grid (64,64)
// ---------------------------------------------------------------------------
__global__ __launch_bounds__(256) void corr_kernel(
    const float* __restrict__ lf, const float* __restrict__ mf,
    const float* __restrict__ sf, const float* __restrict__ s,
    float* __restrict__ lc, float* __restrict__ mc, float* __restrict__ sc)
{
    const int b = blockIdx.y;
    const int wave = threadIdx.x >> 6, lane = threadIdx.x & 63;
    const int c = blockIdx.x * 4 + wave;
    const int bc = b * 256 + c;

    __shared__ __align__(16) float sp[4][33 * 36];
    __shared__ float tw[4][96];

    float* P = sp[wave];
    for (int i = lane; i < 33 * 36; i += 64) P[i] = 0.0f;
    if (lane < 49) tw[wave][lane]      = lf[(size_t)bc * 49 + lane];
    if (lane < 25) tw[wave][49 + lane] = mf[(size_t)bc * 25 + lane];
    if (lane < 9)  tw[wave][74 + lane] = sf[(size_t)bc * 9 + lane];
    for (int i = lane; i < 841; i += 64) {
        int y = i / 29, x = i - y * 29;
        P[(y + 2) * 36 + (x + 2)] = s[(size_t)bc * 841 + i];
    }
    __syncthreads();

    {
        float t7[49];
        #pragma unroll
        for (int k = 0; k < 49; ++k) t7[k] = tw[wave][k];
        #pragma unroll
        for (int it = 0; it < 3; ++it) {
            int og = lane + it * 64;
            bool v = (og < 189);
            int y = v ? (og / 7) : 0;
            int xg = og - (og / 7) * 7;
            int x0 = xg * 4;
            float a0 = 0, a1 = 0, a2 = 0, a3 = 0;
            #pragma unroll
            for (int dy = 0; dy < 7; ++dy) {
                const float* rp = P + (y + dy) * 36 + x0;
                float4 fA = *(const float4*)rp;
                float4 fB = *(const float4*)(rp + 4);
                float4 fC = *(const float4*)(rp + 8);
                float f[12] = {fA.x, fA.y, fA.z, fA.w, fB.x, fB.y, fB.z, fB.w,
                               fC.x, fC.y, fC.z, fC.w};
                #pragma unroll
                for (int dx = 0; dx < 7; ++dx) {
                    float t = t7[dy * 7 + dx];
                    a0 = fmaf(t, f[dx], a0);
                    a1 = fmaf(t, f[dx + 1], a1);
                    a2 = fmaf(t, f[dx + 2], a2);
                    a3 = fmaf(t, f[dx + 3], a3);
                }
            }
            if (v) {
                size_t o = (size_t)bc * 729 + y * 27 + x0;
                lc[o] = a0;
                lc[o + 1] = a1;
                lc[o + 2] = a2;
                if (x0 + 3 < 27) lc[o + 3] = a3;
            }
        }
    }
    {
        float t5[25];
        #pragma unroll
        for (int k = 0; k < 25; ++k) t5[k] = tw[wave][49 + k];
        #pragma unroll
        for (int it = 0; it < 3; ++it) {
            int og = lane + it * 64;
            bool v = (og < 175);
            int y = v ? (og / 7) : 0;
            int xg = og - (og / 7) * 7;
            int x0 = xg * 4;
            float a0 = 0, a1 = 0, a2 = 0, a3 = 0;
            #pragma unroll
            for (int dy = 0; dy < 5; ++dy) {
                const float* rp = P + (y + 2 + dy) * 36 + x0;
                float4 fA = *(const float4*)rp;
                float4 fB = *(const float4*)(rp + 4);
                float4 fC = *(const float4*)(rp + 8);
                float f[12] = {fA.x, fA.y, fA.z, fA.w, fB.x, fB.y, fB.z, fB.w,
                               fC.x, fC.y, fC.z, fC.w};
                #pragma unroll
                for (int dx = 0; dx < 5; ++dx) {
                    float t = t5[dy * 5 + dx];
                    a0 = fmaf(t, f[2 + dx], a0);
                    a1 = fmaf(t, f[3 + dx], a1);
                    a2 = fmaf(t, f[4 + dx], a2);
                    a3 = fmaf(t, f[5 + dx], a3);
                }
            }
            if (v) {
                size_t o = (size_t)bc * 625 + y * 25 + x0;
                mc[o] = a0;
                if (x0 + 1 < 25) mc[o + 1] = a1;
                if (x0 + 2 < 25) mc[o + 2] = a2;
                if (x0 + 3 < 25) mc[o + 3] = a3;
            }
        }
    }
    {
        float t3[9];
        #pragma unroll
        for (int k = 0; k < 9; ++k) t3[k] = tw[wave][74 + k];
        #pragma unroll
        for (int it = 0; it < 3; ++it) {
            int og = lane + it * 64;
            bool v = (og < 189);
            int y = v ? (og / 7) : 0;
            int xg = og - (og / 7) * 7;
            int x0 = xg * 4;
            float a0 = 0, a1 = 0, a2 = 0, a3 = 0;
            #pragma unroll
            for (int dy = 0; dy < 3; ++dy) {
                const float* rp = P + (y + 2 + dy) * 36 + x0;
                float4 fA = *(const float4*)rp;
                float4 fB = *(const float4*)(rp + 4);
                float f[8] = {fA.x, fA.y, fA.z, fA.w, fB.x, fB.y, fB.z, fB.w};
                #pragma unroll
                for (int dx = 0; dx < 3; ++dx) {
                    float t = t3[dy * 3 + dx];
                    a0 = fmaf(t, f[2 + dx], a0);
                    a1 = fmaf(t, f[3 + dx], a1);
                    a2 = fmaf(t, f[4 + dx], a2);
                    a3 = fmaf(t, f[5 + dx], a3);
                }
            }
            if (v) {
                size_t o = (size_t)bc * 729 + y * 27 + x0;
                sc[o] = a0;
                sc[o + 1] = a1;
                sc[o + 2] = a2;
                if (x0 + 3 < 27) sc[o + 3] = a3;
            }
        }
    }
}

// ---------------------------------------------------------------------------
// head v3: A-staging via async DMA from pre-packed w1hT/w1lT (no VALU pack);
// B (X) packed inline. grid (ceil(Np/128), 64)
// ---------------------------------------------------------------------------
__global__ __launch_bounds__(256) void head_mfma_kernel(
    const float* __restrict__ X,
    const short* __restrict__ w1hT, const short* __restrict__ w1lT,
    const float* __restrict__ b1,
    const float* __restrict__ g1, const float* __restrict__ be1,
    const float* __restrict__ m1, const float* __restrict__ v1,
    const float* __restrict__ w2, const float* __restrict__ b2,
    float* __restrict__ out,
    int Np)
{
    const int b  = blockIdx.y;
    const int p0 = blockIdx.x * 128;
    const int tid = threadIdx.x;
    const int wave = tid >> 6, lane = tid & 63;
    const int l15 = lane & 15, quad = lane >> 4;

    __shared__ __align__(16) short Ah[256 * 32], Al[256 * 32];  // [co][ci] = chunk-linear
    __shared__ __align__(16) short Bh[128 * 40], Bl[128 * 40];
    __shared__ float red[128 * 17];

    floatx4 acc[4][8];
    #pragma unroll
    for (int m = 0; m < 4; ++m)
        #pragma unroll
        for (int n = 0; n < 8; ++n) acc[m][n] = (floatx4){0.f, 0.f, 0.f, 0.f};

    const int cp  = tid & 15;
    const int pxq = tid >> 4;

    for (int k0 = 0; k0 < 256; k0 += 32) {
        // ---- stage A: pure async DMA of the 16 KB chunk (hi + lo) ----
        {
            const int kc = k0 >> 5;
            const short* srcH = w1hT + kc * 8192 + wave * 2048 + lane * 8;
            const short* srcL = w1lT + kc * 8192 + wave * 2048 + lane * 8;
            #pragma unroll
            for (int c = 0; c < 4; ++c) {
                dma16(Ah + wave * 2048 + c * 512, srcH + c * 512);
                dma16(Al + wave * 2048 + c * 512, srcL + c * 512);
            }
        }
        // ---- stage B: pack X[ci pair][4 px] -> [px][ci] ----
        #pragma unroll
        for (int halfp = 0; halfp < 2; ++halfp) {
            int pxl = halfp * 64 + pxq * 4;
            int gp = p0 + pxl;
            const float* r0 = X + ((size_t)(b * 256) + k0 + 2 * cp) * Np + gp;
            const float* r1 = r0 + Np;
            #pragma unroll
            for (int j = 0; j < 4; ++j) {
                float u = (gp + j < Np) ? r0[j] : 0.0f;
                float v = (gp + j < Np) ? r1[j] : 0.0f;
                uint32_t hu = pack_hilo(u), hv = pack_hilo(v);
                int o = (pxl + j) * 40 + 2 * cp;
                *(uint32_t*)(Bh + o) = (hu >> 16) | (hv & 0xFFFF0000u);
                *(uint32_t*)(Bl + o) = (hu & 0xFFFFu) | (hv << 16);
            }
        }
        __syncthreads();   // drains vmcnt (DMA) + lgkm (ds_write) then barrier
        short8 amh[4], aml[4];
        #pragma unroll
        for (int m = 0; m < 4; ++m) {
            int ao = (wave * 64 + m * 16 + l15) * 32 + quad * 8;
            amh[m] = *(const short8*)(Ah + ao);
            aml[m] = *(const short8*)(Al + ao);
        }
        #pragma unroll
        for (int n = 0; n < 8; ++n) {
            int bo = (n * 16 + l15) * 40 + quad * 8;
            short8 bh = *(const short8*)(Bh + bo);
            short8 bl = *(const short8*)(Bl + bo);
            #pragma unroll
            for (int m = 0; m < 4; ++m) {
                acc[m][n] = __builtin_amdgcn_mfma_f32_16x16x32_bf16(amh[m], bh, acc[m][n], 0, 0, 0);
                acc[m][n] = __builtin_amdgcn_mfma_f32_16x16x32_bf16(amh[m], bl, acc[m][n], 0, 0, 0);
                acc[m][n] = __builtin_amdgcn_mfma_f32_16x16x32_bf16(aml[m], bh, acc[m][n], 0, 0, 0);
            }
        }
        __syncthreads();
    }

    float Ac[16], Oc[16], Wc[16];
    #pragma unroll
    for (int m = 0; m < 4; ++m)
        #pragma unroll
        for (int reg = 0; reg < 4; ++reg) {
            int co = wave * 64 + m * 16 + quad * 4 + reg;
            float A = g1[co] * rsqrtf(v1[co] + 1e-5f);
            Ac[m * 4 + reg] = A;
            Oc[m * 4 + reg] = fmaf(b1[co] - m1[co], A, be1[co]);
            Wc[m * 4 + reg] = w2[co];
        }
    #pragma unroll
    for (int n = 0; n < 8; ++n) {
        float part = 0.0f;
        #pragma unroll
        for (int m = 0; m < 4; ++m)
            #pragma unroll
            for (int reg = 0; reg < 4; ++reg) {
                float y = fmaxf(fmaf(acc[m][n][reg], Ac[m * 4 + reg], Oc[m * 4 + reg]), 0.0f);
                part = fmaf(Wc[m * 4 + reg], y, part);
            }
        red[(n * 16 + l15) * 17 + wave * 4 + quad] = part;
    }
    __syncthreads();
    if (tid < 128) {
        float z = b2[0];
        #pragma unroll
        for (int k = 0; k < 16; ++k) z += red[tid * 17 + k];
        if (p0 + tid < Np)
            out[(size_t)b * Np + p0 + tid] = 1.0f / (1.0f + expf(-z));
    }
}

// ---------------------------------------------------------------------------
extern "C" void kernel_launch(void* const* d_in, const int* in_sizes, int n_in,
                              void* d_out, int out_size, void* d_ws, size_t ws_size,
                              hipStream_t stream)
{
    const float* large  = (const float*)d_in[0];
    const float* medium = (const float*)d_in[1];
    const float* small  = (const float*)d_in[2];
    const float* search = (const float*)d_in[3];
    const float* wt  = (const float*)d_in[4];
    const float* bt  = (const float*)d_in[5];
    const float* gt  = (const float*)d_in[6];
    const float* bet = (const float*)d_in[7];
    const float* mt  = (const float*)d_in[8];
    const float* vt  = (const float*)d_in[9];
    const float* wsc = (const float*)d_in[10];
    const float* bs  = (const float*)d_in[11];
    const float* gs  = (const float*)d_in[12];
    const float* bes = (const float*)d_in[13];
    const float* ms  = (const float*)d_in[14];
    const float* vs  = (const float*)d_in[15];
    const float* w1  = (const float*)d_in[16];
    const float* b1  = (const float*)d_in[17];
    const float* g1  = (const float*)d_in[18];
    const float* be1 = (const float*)d_in[19];
    const float* m1  = (const float*)d_in[20];
    const float* v1  = (const float*)d_in[21];
    const float* w2  = (const float*)d_in[22];
    const float* b2  = (const float*)d_in[23];

    float* ws = (float*)d_ws;
    size_t off = 0;
    float* lf = ws + off; off += (size_t)64 * 256 * 49;
    float* mf = ws + off; off += (size_t)64 * 256 * 25;
    float* sf = ws + off; off += (size_t)64 * 256 * 9;
    float* sq = ws + off; off += (size_t)64 * 256 * 841;
    float* lc = ws + off; off += (size_t)64 * 256 * 729;
    float* mc = ws + off; off += (size_t)64 * 256 * 625;
    float* sc = ws + off; off += (size_t)64 * 256 * 729;

    // Aliased prep buffers (dead before corr writes lc/mc/sc):
    short* xh_s = (short*)lc;
    short* xl_s = (short*)lc + 15745024;
    short* base = (short*)sc;
    short* xh_L = base;
    short* xl_L = base + 1327104;
    short* xh_M = base + 2654208;
    short* xl_M = base + 3457024;
    short* xh_S = base + 4259840;
    short* xl_S = base + 4669440;
    short* wh_t = base + 5079040;
    short* wl_t = base + 5668864;
    short* wh_s = base + 6258688;
    short* wl_s = base + 6848512;
    // w1 packed buffers live in sq (dead after corr; written after corr):
    short* w1hT = (short*)sq;
    short* w1lT = (short*)sq + 65536;

    dim3 blk(256);
    prep_w_both<<<dim3(256), blk, 0, stream>>>(wt, wh_t, wl_t, wsc, wh_s, wl_s);
    prep_x_all<<<dim3(20, 4, 64), blk, 0, stream>>>(
        search, xh_s, xl_s, large, xh_L, xl_L,
        medium, xh_M, xl_M, small, xh_S, xl_S);

    conv_mfma_tmpl<<<dim3(2, 192), blk, 0, stream>>>(
        xh_L, xl_L, xh_M, xl_M, xh_S, xl_S, wh_t, wl_t,
        bt, gt, bet, mt, vt, lf, mf, sf);
    conv_mfma_search<<<dim3(896), blk, 0, stream>>>(
        xh_s, xl_s, wh_s, wl_s, bs, gs, bes, ms, vs, sq);

    corr_kernel<<<dim3(64, 64), blk, 0, stream>>>(lf, mf, sf, sq, lc, mc, sc);

    // pack w1 into (now dead) sq region, then fused heads
    prep_w1<<<dim3(64), blk, 0, stream>>>(w1, w1hT, w1lT);

    float* outp = (float*)d_out;
    head_mfma_kernel<<<dim3(6, 64), blk, 0, stream>>>(lc, w1hT, w1lT, b1, g1, be1, m1, v1, w2, b2, outp, 729);
    head_mfma_kernel<<<dim3(5, 64), blk, 0, stream>>>(mc, w1hT, w1lT, b1, g1, be1, m1, v1, w2, b2, outp + 46656, 625);
    head_mfma_kernel<<<dim3(6, 64), blk, 0, stream>>>(sc, w1hT, w1lT, b1, g1, be1, m1, v1, w2, b2, outp + 86656, 729);
}

// Round 9
// 714.291 us; speedup vs baseline: 2.3235x; 1.0704x over previous
//
#include <hip/hip_runtime.h>
#include <math.h>
#include <stdint.h>

typedef __attribute__((ext_vector_type(8))) short short8;
typedef __attribute__((ext_vector_type(4))) float floatx4;

// fp32 -> (bf16 hi | bf16 lo) packed u32.  hi = RNE(x), lo = RNE(x - hi).
__device__ __forceinline__ uint32_t pack_hilo(float x) {
    uint32_t u = __float_as_uint(x);
    uint32_t hi = (u + 0x7FFFu + ((u >> 16) & 1u)) & 0xFFFF0000u;
    float r = x - __uint_as_float(hi);
    uint32_t v = __float_as_uint(r);
    uint32_t lo = ((v + 0x7FFFu + ((v >> 16) & 1u)) >> 16) & 0xFFFFu;
    return hi | lo;
}

// async global->LDS DMA, 16 B per lane; lds dest must be wave-uniform base.
__device__ __forceinline__ void dma16(short* lds, const short* g) {
    __builtin_amdgcn_global_load_lds(
        (const __attribute__((address_space(1))) unsigned int*)g,
        (__attribute__((address_space(3))) unsigned int*)lds,
        16, 0, 0);
}

// ---------------------------------------------------------------------------
// Fused prep: all four activation tensors -> hi/lo split, one dispatch.
// grid (20, 4, 64): bx 0..15 search(961), 16..17 large(81), 18 med(49), 19 small(25)
// ---------------------------------------------------------------------------
__global__ __launch_bounds__(256) void prep_x_all(
    const float* __restrict__ xs, short* __restrict__ xhS, short* __restrict__ xlS,
    const float* __restrict__ xL, short* __restrict__ xhL, short* __restrict__ xlL,
    const float* __restrict__ xM, short* __restrict__ xhM, short* __restrict__ xlM,
    const float* __restrict__ xSm, short* __restrict__ xhSm, short* __restrict__ xlSm)
{
    const int bx = blockIdx.x;
    const float* x; short *xh, *xl; int HW, p0;
    if (bx < 16)      { x = xs;  xh = xhS;  xl = xlS;  HW = 961; p0 = bx * 64; }
    else if (bx < 18) { x = xL;  xh = xhL;  xl = xlL;  HW = 81;  p0 = (bx - 16) * 64; }
    else if (bx < 19) { x = xM;  xh = xhM;  xl = xlM;  HW = 49;  p0 = 0; }
    else              { x = xSm; xh = xhSm; xl = xlSm; HW = 25;  p0 = 0; }

    const int b = blockIdx.z, c0 = blockIdx.y * 64;
    const int tid = threadIdx.x;
    const int a = tid & 63, g = tid >> 6;
    __shared__ uint32_t t[64][65];
    #pragma unroll
    for (int i = 0; i < 16; ++i) {
        int c = g + i * 4;
        int p = p0 + a;
        float v = (p < HW) ? x[((size_t)(b * 256) + c0 + c) * HW + p] : 0.0f;
        t[c][a] = pack_hilo(v);
    }
    __syncthreads();
    const int j = tid & 31;
    const int gg = tid >> 5;
    #pragma unroll
    for (int i = 0; i < 8; ++i) {
        int p = gg + i * 8;
        if (p0 + p < HW) {
            uint32_t w0 = t[2 * j][p], w1 = t[2 * j + 1][p];
            size_t o = ((size_t)b * HW + p0 + p) * 256 + c0 + 2 * j;
            *(uint32_t*)(xh + o) = (w0 >> 16) | (w1 & 0xFFFF0000u);
            *(uint32_t*)(xl + o) = (w0 & 0xFFFFu) | (w1 << 16);
        }
    }
}

// ---------------------------------------------------------------------------
// Prep both conv weights: bx<128 -> wt, else wsc. grid (256)
// ---------------------------------------------------------------------------
__global__ __launch_bounds__(256) void prep_w_both(
    const float* __restrict__ wA, short* __restrict__ whA, short* __restrict__ wlA,
    const float* __restrict__ wB, short* __restrict__ whB, short* __restrict__ wlB)
{
    int bx = blockIdx.x;
    const float* w; short *wh, *wl;
    if (bx < 128) { w = wA; wh = whA; wl = wlA; }
    else          { w = wB; wh = whB; wl = wlB; bx -= 128; }
    const int idx = bx * 256 + threadIdx.x;
    const int co = idx >> 7, jp = idx & 127;
    const float* s0 = w + ((size_t)co * 256 + 2 * jp) * 9;
    #pragma unroll
    for (int r = 0; r < 9; ++r) {
        uint32_t q0 = pack_hilo(s0[r]);
        uint32_t q1 = pack_hilo(s0[9 + r]);
        size_t o = (size_t)r * 65536 + (size_t)co * 256 + 2 * jp;
        *(uint32_t*)(wh + o) = (q0 >> 16) | (q1 & 0xFFFF0000u);
        *(uint32_t*)(wl + o) = (q0 & 0xFFFFu) | (q1 << 16);
    }
}

// ---------------------------------------------------------------------------
// Prep w1 (256,256) fp32 -> chunk-major hi/lo: w1hT[k][co][ci&31], k=ci>>5.
// grid (64). Launched AFTER corr (lives in dead sq region).
// ---------------------------------------------------------------------------
__global__ __launch_bounds__(256) void prep_w1(
    const float* __restrict__ w1, short* __restrict__ w1hT, short* __restrict__ w1lT)
{
    const int idx = (blockIdx.x * 256 + threadIdx.x) * 4;
    const int co = idx >> 8, ci = idx & 255;
    const int pos = (ci >> 5) * 8192 + co * 32 + (ci & 31);
    float4 v4 = *(const float4*)(w1 + (size_t)co * 256 + ci);
    uint32_t pa = pack_hilo(v4.x), pb = pack_hilo(v4.y);
    uint32_t pc = pack_hilo(v4.z), pd = pack_hilo(v4.w);
    uint2 uh, ul;
    uh.x = (pa >> 16) | (pb & 0xFFFF0000u);
    uh.y = (pc >> 16) | (pd & 0xFFFF0000u);
    ul.x = (pa & 0xFFFFu) | (pb << 16);
    ul.y = (pc & 0xFFFFu) | (pd << 16);
    *(uint2*)(w1hT + pos) = uh;
    *(uint2*)(w1lT + pos) = ul;
}

// ===========================================================================
// MFMA conv body, async-DMA double-buffered (R7-proven).
// ===========================================================================
__device__ __forceinline__ void conv_body(
    const short* __restrict__ xh, const short* __restrict__ xl,
    const short* __restrict__ wh, const short* __restrict__ wl,
    const float* __restrict__ bias,
    const float* __restrict__ gam, const float* __restrict__ bet,
    const float* __restrict__ mu,  const float* __restrict__ var,
    float* __restrict__ out,
    int b, int co0, int p0, int H, int W, short* smem)
{
    const int HW = H * W;
    const int Wo = W - 2, P = Wo * Wo;
    const int tid  = threadIdx.x;
    const int wave = tid >> 6, lane = tid & 63;
    const int l15  = lane & 15, quad = lane >> 4;

    int NT = (P - p0 + 15) >> 4;
    if (NT > 8) NT = 8;

    const int lsub = lane >> 2;
    const int lq   = (lane & 3) * 8;
    const size_t abase0 = (size_t)(co0 + wave * 32 + lsub) * 256 + lq;
    const size_t abase1 = abase0 + 16 * 256;
    int pr0 = p0 + wave * 32 + lsub;      if (pr0 >= P) pr0 = 0;
    int pr1 = p0 + wave * 32 + 16 + lsub; if (pr1 >= P) pr1 = 0;
    const size_t bbase0 = ((size_t)b * HW + (pr0 / Wo) * W + (pr0 % Wo)) * 256 + lq;
    const size_t bbase1 = ((size_t)b * HW + (pr1 / Wo) * W + (pr1 % Wo)) * 256 + lq;

    const int ldsw = wave * 1024;

    floatx4 acc[2][8];
    #pragma unroll
    for (int s = 0; s < 2; ++s)
        #pragma unroll
        for (int t = 0; t < 8; ++t) acc[s][t] = (floatx4){0.f, 0.f, 0.f, 0.f};

    const int fA = (wave * 32 + l15) * 32 + quad * 8;
    int fB[8];
    #pragma unroll
    for (int t = 0; t < 8; ++t) fB[t] = (t * 16 + l15) * 32 + quad * 8;

    auto issue = [&](int k, int q) {
        const int r = k >> 3, c4 = k & 7;
        const int ry = r / 3, rx = r - ry * 3;
        const size_t ga = (size_t)r * 65536 + c4 * 32;
        const size_t gb = (size_t)(ry * W + rx) * 256 + c4 * 32;
        short* base = smem + q * 16384;
        dma16(base + ldsw,                wh + ga + abase0);
        dma16(base + ldsw + 512,          wh + ga + abase1);
        dma16(base + 4096 + ldsw,         wl + ga + abase0);
        dma16(base + 4096 + ldsw + 512,   wl + ga + abase1);
        dma16(base + 8192 + ldsw,         xh + gb + bbase0);
        dma16(base + 8192 + ldsw + 512,   xh + gb + bbase1);
        dma16(base + 12288 + ldsw,        xl + gb + bbase0);
        dma16(base + 12288 + ldsw + 512,  xl + gb + bbase1);
    };

    issue(0, 0);
    for (int k = 0; k < 72; ++k) {
        const int q = k & 1;
        asm volatile("s_barrier" ::: "memory");
        if (k + 1 < 72) {
            issue(k + 1, q ^ 1);
            asm volatile("s_waitcnt vmcnt(8)" ::: "memory");
        } else {
            asm volatile("s_waitcnt vmcnt(0)" ::: "memory");
        }
        asm volatile("s_barrier" ::: "memory");
        const short* bq = smem + q * 16384;
        short8 a0h = *(const short8*)(bq + fA);
        short8 a1h = *(const short8*)(bq + fA + 512);
        short8 a0l = *(const short8*)(bq + 4096 + fA);
        short8 a1l = *(const short8*)(bq + 4096 + fA + 512);
        #pragma unroll
        for (int t = 0; t < 8; ++t) {
            if (t < NT) {
                short8 vh = *(const short8*)(bq + 8192 + fB[t]);
                short8 vl = *(const short8*)(bq + 12288 + fB[t]);
                acc[0][t] = __builtin_amdgcn_mfma_f32_16x16x32_bf16(a0h, vh, acc[0][t], 0, 0, 0);
                acc[1][t] = __builtin_amdgcn_mfma_f32_16x16x32_bf16(a1h, vh, acc[1][t], 0, 0, 0);
                acc[0][t] = __builtin_amdgcn_mfma_f32_16x16x32_bf16(a0h, vl, acc[0][t], 0, 0, 0);
                acc[1][t] = __builtin_amdgcn_mfma_f32_16x16x32_bf16(a1h, vl, acc[1][t], 0, 0, 0);
                acc[0][t] = __builtin_amdgcn_mfma_f32_16x16x32_bf16(a0l, vh, acc[0][t], 0, 0, 0);
                acc[1][t] = __builtin_amdgcn_mfma_f32_16x16x32_bf16(a1l, vh, acc[1][t], 0, 0, 0);
            }
        }
    }

    #pragma unroll
    for (int s = 0; s < 2; ++s) {
        const int cobase = co0 + wave * 32 + s * 16 + quad * 4;
        #pragma unroll
        for (int reg = 0; reg < 4; ++reg) {
            const int co = cobase + reg;
            const float A   = gam[co] * rsqrtf(var[co] + 1e-5f);
            const float OFF = fmaf(bias[co] - mu[co], A, bet[co]);
            float* orow = out + ((size_t)(b * 256 + co)) * P;
            #pragma unroll
            for (int t = 0; t < 8; ++t) {
                int px = p0 + t * 16 + l15;
                if (px < P)
                    orow[px] = fmaxf(fmaf(acc[s][t][reg], A, OFF), 0.0f);
            }
        }
    }
}

// ---------------------------------------------------------------------------
// conv_mfma_all: search (blocks 0..895, XCD swizzle) + all 3 template scales
// (blocks 896..1279) in ONE dispatch — tmpl fills search's ramp/drain slots.
// ---------------------------------------------------------------------------
__global__ __launch_bounds__(256) void conv_mfma_all(
    const short* __restrict__ xh_s, const short* __restrict__ xl_s,
    const short* __restrict__ wh_s, const short* __restrict__ wl_s,
    const float* __restrict__ bs, const float* __restrict__ gs,
    const float* __restrict__ bes, const float* __restrict__ ms,
    const float* __restrict__ vs, float* __restrict__ sq,
    const short* __restrict__ xhL, const short* __restrict__ xlL,
    const short* __restrict__ xhM, const short* __restrict__ xlM,
    const short* __restrict__ xhS, const short* __restrict__ xlS,
    const short* __restrict__ wh_t, const short* __restrict__ wl_t,
    const float* __restrict__ bt, const float* __restrict__ gt,
    const float* __restrict__ bet, const float* __restrict__ mt,
    const float* __restrict__ vt,
    float* __restrict__ lf, float* __restrict__ mf, float* __restrict__ sf)
{
    __shared__ __align__(16) short smem[32768];
    const int i = blockIdx.x;
    if (i < 896) {
        const int xcd = i & 7, slot = i >> 3;
        const int bl = slot / 14, tile = slot - bl * 14;
        const int b = xcd * 8 + bl;
        conv_body(xh_s, xl_s, wh_s, wl_s, bs, gs, bes, ms, vs, sq,
                  b, (tile & 1) * 128, (tile >> 1) * 128, 31, 31, smem);
    } else {
        const int j = i - 896;                 // 0..383
        const int cohalf = j & 1, sb = j >> 1; // sb 0..191
        const int scale = sb >> 6, b = sb & 63;
        const short* xh = (scale == 0) ? xhL : (scale == 1) ? xhM : xhS;
        const short* xl = (scale == 0) ? xlL : (scale == 1) ? xlM : xlS;
        float* out      = (scale == 0) ? lf : (scale == 1) ? mf : sf;
        const int H     = (scale == 0) ? 9 : (scale == 1) ? 7 : 5;
        conv_body(xh, xl, wh_t, wl_t, bt, gt, bet, mt, vt, out,
                  b, cohalf * 128, 0, H, H, smem);
    }
}

// ---------------------------------------------------------------------------
// corr v2 (R4-proven). grid (64,64)
// ---------------------------------------------------------------------------
__global__ __launch_bounds__(256) void corr_kernel(
    const float* __restrict__ lf, const float* __restrict__ mf,
    const float* __restrict__ sf, const float* __restrict__ s,
    float* __restrict__ lc, float* __restrict__ mc, float* __restrict__ sc)
{
    const int b = blockIdx.y;
    const int wave = threadIdx.x >> 6, lane = threadIdx.x & 63;
    const int c = blockIdx.x * 4 + wave;
    const int bc = b * 256 + c;

    __shared__ __align__(16) float sp[4][33 * 36];
    __shared__ float tw[4][96];

    float* P = sp[wave];
    for (int i = lane; i < 33 * 36; i += 64) P[i] = 0.0f;
    if (lane < 49) tw[wave][lane]      = lf[(size_t)bc * 49 + lane];
    if (lane < 25) tw[wave][49 + lane] = mf[(size_t)bc * 25 + lane];
    if (lane < 9)  tw[wave][74 + lane] = sf[(size_t)bc * 9 + lane];
    for (int i = lane; i < 841; i += 64) {
        int y = i / 29, x = i - y * 29;
        P[(y + 2) * 36 + (x + 2)] = s[(size_t)bc * 841 + i];
    }
    __syncthreads();

    {
        float t7[49];
        #pragma unroll
        for (int k = 0; k < 49; ++k) t7[k] = tw[wave][k];
        #pragma unroll
        for (int it = 0; it < 3; ++it) {
            int og = lane + it * 64;
            bool v = (og < 189);
            int y = v ? (og / 7) : 0;
            int xg = og - (og / 7) * 7;
            int x0 = xg * 4;
            float a0 = 0, a1 = 0, a2 = 0, a3 = 0;
            #pragma unroll
            for (int dy = 0; dy < 7; ++dy) {
                const float* rp = P + (y + dy) * 36 + x0;
                float4 fA = *(const float4*)rp;
                float4 fB = *(const float4*)(rp + 4);
                float4 fC = *(const float4*)(rp + 8);
                float f[12] = {fA.x, fA.y, fA.z, fA.w, fB.x, fB.y, fB.z, fB.w,
                               fC.x, fC.y, fC.z, fC.w};
                #pragma unroll
                for (int dx = 0; dx < 7; ++dx) {
                    float t = t7[dy * 7 + dx];
                    a0 = fmaf(t, f[dx], a0);
                    a1 = fmaf(t, f[dx + 1], a1);
                    a2 = fmaf(t, f[dx + 2], a2);
                    a3 = fmaf(t, f[dx + 3], a3);
                }
            }
            if (v) {
                size_t o = (size_t)bc * 729 + y * 27 + x0;
                lc[o] = a0;
                lc[o + 1] = a1;
                lc[o + 2] = a2;
                if (x0 + 3 < 27) lc[o + 3] = a3;
            }
        }
    }
    {
        float t5[25];
        #pragma unroll
        for (int k = 0; k < 25; ++k) t5[k] = tw[wave][49 + k];
        #pragma unroll
        for (int it = 0; it < 3; ++it) {
            int og = lane + it * 64;
            bool v = (og < 175);
            int y = v ? (og / 7) : 0;
            int xg = og - (og / 7) * 7;
            int x0 = xg * 4;
            float a0 = 0, a1 = 0, a2 = 0, a3 = 0;
            #pragma unroll
            for (int dy = 0; dy < 5; ++dy) {
                const float* rp = P + (y + 2 + dy) * 36 + x0;
                float4 fA = *(const float4*)rp;
                float4 fB = *(const float4*)(rp + 4);
                float4 fC = *(const float4*)(rp + 8);
                float f[12] = {fA.x, fA.y, fA.z, fA.w, fB.x, fB.y, fB.z, fB.w,
                               fC.x, fC.y, fC.z, fC.w};
                #pragma unroll
                for (int dx = 0; dx < 5; ++dx) {
                    float t = t5[dy * 5 + dx];
                    a0 = fmaf(t, f[2 + dx], a0);
                    a1 = fmaf(t, f[3 + dx], a1);
                    a2 = fmaf(t, f[4 + dx], a2);
                    a3 = fmaf(t, f[5 + dx], a3);
                }
            }
            if (v) {
                size_t o = (size_t)bc * 625 + y * 25 + x0;
                mc[o] = a0;
                if (x0 + 1 < 25) mc[o + 1] = a1;
                if (x0 + 2 < 25) mc[o + 2] = a2;
                if (x0 + 3 < 25) mc[o + 3] = a3;
            }
        }
    }
    {
        float t3[9];
        #pragma unroll
        for (int k = 0; k < 9; ++k) t3[k] = tw[wave][74 + k];
        #pragma unroll
        for (int it = 0; it < 3; ++it) {
            int og = lane + it * 64;
            bool v = (og < 189);
            int y = v ? (og / 7) : 0;
            int xg = og - (og / 7) * 7;
            int x0 = xg * 4;
            float a0 = 0, a1 = 0, a2 = 0, a3 = 0;
            #pragma unroll
            for (int dy = 0; dy < 3; ++dy) {
                const float* rp = P + (y + 2 + dy) * 36 + x0;
                float4 fA = *(const float4*)rp;
                float4 fB = *(const float4*)(rp + 4);
                float f[8] = {fA.x, fA.y, fA.z, fA.w, fB.x, fB.y, fB.z, fB.w};
                #pragma unroll
                for (int dx = 0; dx < 3; ++dx) {
                    float t = t3[dy * 3 + dx];
                    a0 = fmaf(t, f[2 + dx], a0);
                    a1 = fmaf(t, f[3 + dx], a1);
                    a2 = fmaf(t, f[4 + dx], a2);
                    a3 = fmaf(t, f[5 + dx], a3);
                }
            }
            if (v) {
                size_t o = (size_t)bc * 729 + y * 27 + x0;
                sc[o] = a0;
                sc[o + 1] = a1;
                sc[o + 2] = a2;
                if (x0 + 3 < 27) sc[o + 3] = a3;
            }
        }
    }
}

// ---------------------------------------------------------------------------
// head v3 merged: all 3 sections in one dispatch. grid (17, 64):
// bx 0..5 -> lc (Np=729, off 0), 6..10 -> mc (625, 46656), 11..16 -> sc (729, 86656)
// ---------------------------------------------------------------------------
__global__ __launch_bounds__(256) void head_mfma_kernel(
    const float* __restrict__ lc, const float* __restrict__ mc,
    const float* __restrict__ sc,
    const short* __restrict__ w1hT, const short* __restrict__ w1lT,
    const float* __restrict__ b1,
    const float* __restrict__ g1, const float* __restrict__ be1,
    const float* __restrict__ m1, const float* __restrict__ v1,
    const float* __restrict__ w2, const float* __restrict__ b2,
    float* __restrict__ out)
{
    const int bx = blockIdx.x;
    const float* X; int Np, ooff, p0;
    if (bx < 6)       { X = lc; Np = 729; ooff = 0;     p0 = bx * 128; }
    else if (bx < 11) { X = mc; Np = 625; ooff = 46656; p0 = (bx - 6) * 128; }
    else              { X = sc; Np = 729; ooff = 86656; p0 = (bx - 11) * 128; }

    const int b  = blockIdx.y;
    const int tid = threadIdx.x;
    const int wave = tid >> 6, lane = tid & 63;
    const int l15 = lane & 15, quad = lane >> 4;

    __shared__ __align__(16) short Ah[256 * 32], Al[256 * 32];
    __shared__ __align__(16) short Bh[128 * 40], Bl[128 * 40];
    __shared__ float red[128 * 17];

    floatx4 acc[4][8];
    #pragma unroll
    for (int m = 0; m < 4; ++m)
        #pragma unroll
        for (int n = 0; n < 8; ++n) acc[m][n] = (floatx4){0.f, 0.f, 0.f, 0.f};

    const int cp  = tid & 15;
    const int pxq = tid >> 4;

    for (int k0 = 0; k0 < 256; k0 += 32) {
        {
            const int kc = k0 >> 5;
            const short* srcH = w1hT + kc * 8192 + wave * 2048 + lane * 8;
            const short* srcL = w1lT + kc * 8192 + wave * 2048 + lane * 8;
            #pragma unroll
            for (int c = 0; c < 4; ++c) {
                dma16(Ah + wave * 2048 + c * 512, srcH + c * 512);
                dma16(Al + wave * 2048 + c * 512, srcL + c * 512);
            }
        }
        #pragma unroll
        for (int halfp = 0; halfp < 2; ++halfp) {
            int pxl = halfp * 64 + pxq * 4;
            int gp = p0 + pxl;
            const float* r0 = X + ((size_t)(b * 256) + k0 + 2 * cp) * Np + gp;
            const float* r1 = r0 + Np;
            #pragma unroll
            for (int j = 0; j < 4; ++j) {
                float u = (gp + j < Np) ? r0[j] : 0.0f;
                float v = (gp + j < Np) ? r1[j] : 0.0f;
                uint32_t hu = pack_hilo(u), hv = pack_hilo(v);
                int o = (pxl + j) * 40 + 2 * cp;
                *(uint32_t*)(Bh + o) = (hu >> 16) | (hv & 0xFFFF0000u);
                *(uint32_t*)(Bl + o) = (hu & 0xFFFFu) | (hv << 16);
            }
        }
        __syncthreads();
        short8 amh[4], aml[4];
        #pragma unroll
        for (int m = 0; m < 4; ++m) {
            int ao = (wave * 64 + m * 16 + l15) * 32 + quad * 8;
            amh[m] = *(const short8*)(Ah + ao);
            aml[m] = *(const short8*)(Al + ao);
        }
        #pragma unroll
        for (int n = 0; n < 8; ++n) {
            int bo = (n * 16 + l15) * 40 + quad * 8;
            short8 bh = *(const short8*)(Bh + bo);
            short8 bl = *(const short8*)(Bl + bo);
            #pragma unroll
            for (int m = 0; m < 4; ++m) {
                acc[m][n] = __builtin_amdgcn_mfma_f32_16x16x32_bf16(amh[m], bh, acc[m][n], 0, 0, 0);
                acc[m][n] = __builtin_amdgcn_mfma_f32_16x16x32_bf16(amh[m], bl, acc[m][n], 0, 0, 0);
                acc[m][n] = __builtin_amdgcn_mfma_f32_16x16x32_bf16(aml[m], bh, acc[m][n], 0, 0, 0);
            }
        }
        __syncthreads();
    }

    float Ac[16], Oc[16], Wc[16];
    #pragma unroll
    for (int m = 0; m < 4; ++m)
        #pragma unroll
        for (int reg = 0; reg < 4; ++reg) {
            int co = wave * 64 + m * 16 + quad * 4 + reg;
            float A = g1[co] * rsqrtf(v1[co] + 1e-5f);
            Ac[m * 4 + reg] = A;
            Oc[m * 4 + reg] = fmaf(b1[co] - m1[co], A, be1[co]);
            Wc[m * 4 + reg] = w2[co];
        }
    #pragma unroll
    for (int n = 0; n < 8; ++n) {
        float part = 0.0f;
        #pragma unroll
        for (int m = 0; m < 4; ++m)
            #pragma unroll
            for (int reg = 0; reg < 4; ++reg) {
                float y = fmaxf(fmaf(acc[m][n][reg], Ac[m * 4 + reg], Oc[m * 4 + reg]), 0.0f);
                part = fmaf(Wc[m * 4 + reg], y, part);
            }
        red[(n * 16 + l15) * 17 + wave * 4 + quad] = part;
    }
    __syncthreads();
    if (tid < 128) {
        float z = b2[0];
        #pragma unroll
        for (int k = 0; k < 16; ++k) z += red[tid * 17 + k];
        if (p0 + tid < Np)
            out[ooff + (size_t)b * Np + p0 + tid] = 1.0f / (1.0f + expf(-z));
    }
}

// ---------------------------------------------------------------------------
extern "C" void kernel_launch(void* const* d_in, const int* in_sizes, int n_in,
                              void* d_out, int out_size, void* d_ws, size_t ws_size,
                              hipStream_t stream)
{
    const float* large  = (const float*)d_in[0];
    const float* medium = (const float*)d_in[1];
    const float* small  = (const float*)d_in[2];
    const float* search = (const float*)d_in[3];
    const float* wt  = (const float*)d_in[4];
    const float* bt  = (const float*)d_in[5];
    const float* gt  = (const float*)d_in[6];
    const float* bet = (const float*)d_in[7];
    const float* mt  = (const float*)d_in[8];
    const float* vt  = (const float*)d_in[9];
    const float* wsc = (const float*)d_in[10];
    const float* bs  = (const float*)d_in[11];
    const float* gs  = (const float*)d_in[12];
    const float* bes = (const float*)d_in[13];
    const float* ms  = (const float*)d_in[14];
    const float* vs  = (const float*)d_in[15];
    const float* w1  = (const float*)d_in[16];
    const float* b1  = (const float*)d_in[17];
    const float* g1  = (const float*)d_in[18];
    const float* be1 = (const float*)d_in[19];
    const float* m1  = (const float*)d_in[20];
    const float* v1  = (const float*)d_in[21];
    const float* w2  = (const float*)d_in[22];
    const float* b2  = (const float*)d_in[23];

    float* ws = (float*)d_ws;
    size_t off = 0;
    float* lf = ws + off; off += (size_t)64 * 256 * 49;
    float* mf = ws + off; off += (size_t)64 * 256 * 25;
    float* sf = ws + off; off += (size_t)64 * 256 * 9;
    float* sq = ws + off; off += (size_t)64 * 256 * 841;
    float* lc = ws + off; off += (size_t)64 * 256 * 729;
    float* mc = ws + off; off += (size_t)64 * 256 * 625;
    float* sc = ws + off; off += (size_t)64 * 256 * 729;

    // Aliased prep buffers (dead before corr writes lc/mc/sc):
    short* xh_s = (short*)lc;
    short* xl_s = (short*)lc + 15745024;
    short* base = (short*)sc;
    short* xh_L = base;
    short* xl_L = base + 1327104;
    short* xh_M = base + 2654208;
    short* xl_M = base + 3457024;
    short* xh_S = base + 4259840;
    short* xl_S = base + 4669440;
    short* wh_t = base + 5079040;
    short* wl_t = base + 5668864;
    short* wh_s = base + 6258688;
    short* wl_s = base + 6848512;
    // w1 packed buffers live in sq (dead after corr; written after corr):
    short* w1hT = (short*)sq;
    short* w1lT = (short*)sq + 65536;

    dim3 blk(256);
    prep_w_both<<<dim3(256), blk, 0, stream>>>(wt, wh_t, wl_t, wsc, wh_s, wl_s);
    prep_x_all<<<dim3(20, 4, 64), blk, 0, stream>>>(
        search, xh_s, xl_s, large, xh_L, xl_L,
        medium, xh_M, xl_M, small, xh_S, xl_S);

    conv_mfma_all<<<dim3(1280), blk, 0, stream>>>(
        xh_s, xl_s, wh_s, wl_s, bs, gs, bes, ms, vs, sq,
        xh_L, xl_L, xh_M, xl_M, xh_S, xl_S, wh_t, wl_t,
        bt, gt, bet, mt, vt, lf, mf, sf);

    corr_kernel<<<dim3(64, 64), blk, 0, stream>>>(lf, mf, sf, sq, lc, mc, sc);

    // pack w1 into (now dead) sq region, then fused merged heads
    prep_w1<<<dim3(64), blk, 0, stream>>>(w1, w1hT, w1lT);

    head_mfma_kernel<<<dim3(17, 64), blk, 0, stream>>>(
        lc, mc, sc, w1hT, w1lT, b1, g1, be1, m1, v1, w2, b2, (float*)d_out);
}